// Round 22
// baseline (1383.137 us; speedup 1.0000x reference)
//
#include <hip/hip_runtime.h>
#include <hip/hip_bf16.h>

#define HWSZ 65536   // 256*256
#define NPIX 131072  // 2 * HWSZ

typedef unsigned short u16;
typedef __bf16 bf16x8 __attribute__((ext_vector_type(8)));
typedef float f32x4 __attribute__((ext_vector_type(4)));
typedef unsigned short u16x2 __attribute__((ext_vector_type(2)));
typedef unsigned short u16x4 __attribute__((ext_vector_type(4)));
typedef unsigned short u16x8 __attribute__((ext_vector_type(8)));
typedef unsigned short u16x8u __attribute__((ext_vector_type(8), aligned(4)));

__device__ inline u16 f2bf(float f) {
    unsigned int x = __builtin_bit_cast(unsigned int, f);
    unsigned int r = x + 0x7FFFu + ((x >> 16) & 1u);
    return (u16)(r >> 16);
}
__device__ inline float bf2f(u16 u) {
    unsigned int x = ((unsigned int)u) << 16;
    return __builtin_bit_cast(float, x);
}

// ---------------------------------------------------------------------------
// Weight prep (verbatim r5-r21)
// ---------------------------------------------------------------------------
__global__ __launch_bounds__(256) void prep_w(
    const float* __restrict__ w0, const float* __restrict__ w1,
    const float* __restrict__ wi, const float* __restrict__ wo,
    u16* __restrict__ W0p, u16* __restrict__ W1p,
    u16* __restrict__ Wip, u16* __restrict__ Wop)
{
    const int i = blockIdx.x * 256 + threadIdx.x;   // < 73728
    {
        const int r = i / 192, c = i % 192;
        const bool ok = (r < 360) && (c < 180);
        W0p[i] = ok ? f2bf(w0[r * 180 + c]) : (u16)0;
        Wip[i] = ok ? f2bf(wi[r * 180 + c]) : (u16)0;
    }
    {
        const int r = i / 384, c = i % 384;
        W1p[i] = (r < 180 && c < 360) ? f2bf(w1[r * 360 + c]) : (u16)0;
    }
    if (i < 36864) {
        const int r = i / 192, c = i % 192;
        Wop[i] = (r < 180 && c < 180) ? f2bf(wo[r * 180 + c]) : (u16)0;
    }
}

// ---------------------------------------------------------------------------
// conv_v9: reg-staging conv for conv1 (fp32 NCHW input), (N,2) grid.
// launch_bounds(256,8): permit full residency (VGPR 60 fits 8 waves/EU).
// ---------------------------------------------------------------------------
template<int CI, int CO, int G, int INM, int XSTR, bool RELU, int RES, int OUTM, int OSTR>
__global__ __launch_bounds__(256, 8) void conv_v9(
    const void* __restrict__ Xv, const u16* __restrict__ Wp,
    const float* __restrict__ bias, const void* __restrict__ Rv,
    void* __restrict__ Yv)
{
    constexpr int CI_PAD = ((CI + 31) / 32) * 32;
    constexpr int NSTEP  = CI_PAD / 32;
    constexpr int LDK    = 40;

    __shared__ u16 Xt[2][64 * LDK];

    const int tid = threadIdx.x;
    const int co0 = blockIdx.y * 192;
    const int p0   = blockIdx.x << 6;
    const int b    = p0 >> 16;
    const int pix0 = p0 & 65535;
    const int h    = pix0 >> 8;
    const int w0c  = pix0 & 255;
    const int lane = tid & 63, wid = tid >> 6;
    const int lr = lane & 15, lg = lane >> 4;
    const int co_wave = co0 + wid * 48;

    const float* Xf = (const float*)Xv + (size_t)b * CI * HWSZ;
    const u16*   Xh = (const u16*)Xv;

    const int xn  = tid & 63;
    const int k4a = tid >> 6;

    auto loadX = [&](int kt, u16x4 (&r)[2]) {
        #pragma unroll
        for (int it = 0; it < 2; ++it) {
            const int k4 = k4a + it * 4;
            const int c0 = kt + k4 * 4;
            u16x4 v = {0, 0, 0, 0};
            if (c0 < CI) {
                int dh = 0, dw = 0;
                if (G > 0) {
                    const int g = c0 / G;
                    if      (g == 0) dw = 1;
                    else if (g == 1) dw = -1;
                    else if (g == 2) dh = 1;
                    else if (g == 3) dh = -1;
                }
                const int hh = h + dh;
                const int wp = w0c + xn + dw;
                if (hh >= 0 && hh < 256 && wp >= 0 && wp < 256) {
                    if constexpr (INM == 1) {
                        v = *(const u16x4*)&Xh[(size_t)((b << 16) | (hh << 8) | wp) * XSTR + c0];
                    } else {
                        const float* xs = Xf + (size_t)c0 * HWSZ + hh * 256 + wp;
                        #pragma unroll
                        for (int j = 0; j < 4; ++j) v[j] = f2bf(xs[(size_t)j * HWSZ]);
                    }
                }
            }
            r[it] = v;
        }
    };

    auto loadW = [&](int kt, bf16x8 (&a)[3]) {
        #pragma unroll
        for (int mf = 0; mf < 3; ++mf)
            a[mf] = *(const bf16x8*)&Wp[(size_t)(co_wave + mf * 16 + lr) * CI_PAD + kt + lg * 8];
    };

    auto writeLDS = [&](u16x4 (&r)[2], int buf) {
        *(u16x4*)&Xt[buf][xn * LDK + k4a * 4]       = r[0];
        *(u16x4*)&Xt[buf][xn * LDK + (k4a + 4) * 4] = r[1];
    };

    f32x4 acc[3][4] = {};
    u16x4 raw[2][2];
    bf16x8 af[2][3];

    loadX(0, raw[0]);
    loadW(0, af[0]);
    writeLDS(raw[0], 0);

    #pragma unroll
    for (int s = 0; s < NSTEP; ++s) {
        const int cur = s & 1, nxt = cur ^ 1;
        __syncthreads();
        if (s + 1 < NSTEP) {
            loadX((s + 1) * 32, raw[nxt]);
            loadW((s + 1) * 32, af[nxt]);
        }
        bf16x8 bfr[4];
        #pragma unroll
        for (int nf = 0; nf < 4; ++nf)
            bfr[nf] = *(const bf16x8*)&Xt[cur][(nf * 16 + lr) * LDK + lg * 8];
        #pragma unroll
        for (int mf = 0; mf < 3; ++mf)
            #pragma unroll
            for (int nf = 0; nf < 4; ++nf)
                acc[mf][nf] = __builtin_amdgcn_mfma_f32_16x16x32_bf16(
                    af[cur][mf], bfr[nf], acc[mf][nf], 0, 0, 0);
        if (s + 1 < NSTEP) writeLDS(raw[nxt], nxt);
    }

    const float* Rf = (const float*)Rv;
    const u16*   Rh = (const u16*)Rv;
    #pragma unroll
    for (int mf = 0; mf < 3; ++mf) {
        const int co_b = co_wave + mf * 16 + lg * 4;
        if (co_b >= CO) continue;
        #pragma unroll
        for (int nf = 0; nf < 4; ++nf) {
            const int pl = pix0 + nf * 16 + lr;
            const size_t pg = (size_t)p0 + nf * 16 + lr;
            float v[4];
            #pragma unroll
            for (int r = 0; r < 4; ++r) {
                v[r] = acc[mf][nf][r] + bias[co_b + r];
                if (RELU) v[r] = fmaxf(v[r], 0.f);
            }
            if (RES == 1) {
                #pragma unroll
                for (int r = 0; r < 4; ++r)
                    v[r] += Rf[((size_t)(b * CO + co_b + r)) * HWSZ + pl];
            }
            if (RES == 2) {
                u16x4 rr = *(const u16x4*)&Rh[pg * 180 + co_b];
                #pragma unroll
                for (int r = 0; r < 4; ++r) v[r] += bf2f(rr[r]);
            }
            if (OUTM == 1) {
                u16x4 o;
                #pragma unroll
                for (int r = 0; r < 4; ++r) o[r] = f2bf(v[r]);
                *(u16x4*)&((u16*)Yv)[pg * OSTR + co_b] = o;
            } else {
                #pragma unroll
                for (int r = 0; r < 4; ++r)
                    ((float*)Yv)[((size_t)(b * CO + co_b + r)) * HWSZ + pl] = v[r];
            }
        }
    }
}

// ---------------------------------------------------------------------------
// conv_v10 (r21 skeleton + TPB persistent tiles + launch_bounds(256,8)).
// TPB consecutive 64-px tiles per block; LDS reuse fenced by the K-loop's
// trailing __syncthreads. COSPLIT path keeps TPB=1 decode.
// ---------------------------------------------------------------------------
template<int CI, int CO, int G, int XSTR, bool RELU, int RES, int OUTM, int OSTR, bool COSPLIT, int TPB>
__global__ __launch_bounds__(256, 8) void conv_v10(
    const u16* __restrict__ Xh, const u16* __restrict__ Wp,
    const float* __restrict__ bias, const void* __restrict__ Rv,
    void* __restrict__ Yv)
{
    constexpr int CI_PAD = ((CI + 31) / 32) * 32;
    constexpr int NSTEP  = CI_PAD / 32;

    __shared__ u16 Xt[2][256 * 8];   // 2 x 4 KB

    const int tid = threadIdx.x;
    const int bid = blockIdx.x;
    const int lane = tid & 63, wid = tid >> 6;
    const int lr = lane & 15, lg = lane >> 4;

    const int sg  = (wid << 6) | lane;
    const int spx = sg >> 2;
    const int khp = sg & 3;
    const int kh  = khp ^ ((spx >> 1) & 3);

    auto loadW = [&](int co_wave, int kt, bf16x8 (&a)[3]) {
        #pragma unroll
        for (int mf = 0; mf < 3; ++mf)
            a[mf] = *(const bf16x8*)&Wp[(size_t)(co_wave + mf * 16 + lr) * CI_PAD + kt + lg * 8];
    };

    for (int t = 0; t < TPB; ++t) {
        int px_tile, co0;
        if (COSPLIT) {
            co0     = ((bid >> 3) & 1) * 192;
            px_tile = ((bid >> 4) << 3) | (bid & 7);
        } else {
            co0 = blockIdx.y * 192; px_tile = bid * TPB + t;
        }
        const int p0   = px_tile << 6;
        const int b    = p0 >> 16;
        const int pix0 = p0 & 65535;
        const int h    = pix0 >> 8;
        const int w0c  = pix0 & 255;
        const int co_wave = co0 + wid * 48;

        auto stage = [&](int kt, int buf) {
            const int c0 = kt + kh * 8;
            u16* ldst_lane = &Xt[buf][sg * 8];
            int dh = 0, dw = 0; bool uni = true;
            if (G > 0) {
                const int g0 = c0 / G;
                uni = (g0 == (c0 + 7) / G);
                if      (g0 == 0) dw = 1;
                else if (g0 == 1) dw = -1;
                else if (g0 == 2) dh = 1;
                else if (g0 == 3) dh = -1;
            }
            const int hh = h + dh, wp = w0c + spx + dw;
            const bool pxok = (hh >= 0 && hh < 256 && wp >= 0 && wp < 256);
            if (c0 < CI && uni && pxok) {
                const u16* src = &Xh[(size_t)((b << 16) | (hh << 8) | wp) * XSTR + c0];
                u16* wbase = &Xt[buf][(wid << 6) * 8];
                __builtin_amdgcn_global_load_lds(
                    (const __attribute__((address_space(1))) unsigned int*)src,
                    (__attribute__((address_space(3))) unsigned int*)wbase, 16, 0, 0);
            } else {
                u16x8 tt = {0, 0, 0, 0, 0, 0, 0, 0};
                if (c0 < CI && pxok) {
                    #pragma unroll
                    for (int j = 0; j < 8; ++j) {
                        const int c = c0 + j;
                        if (c < CI) {
                            int dh2 = 0, dw2 = 0;
                            if (G > 0) {
                                const int g = c / G;
                                if      (g == 0) dw2 = 1;
                                else if (g == 1) dw2 = -1;
                                else if (g == 2) dh2 = 1;
                                else if (g == 3) dh2 = -1;
                            }
                            const int h2 = h + dh2, w2 = w0c + spx + dw2;
                            if (h2 >= 0 && h2 < 256 && w2 >= 0 && w2 < 256)
                                tt[j] = Xh[(size_t)((b << 16) | (h2 << 8) | w2) * XSTR + c];
                        }
                    }
                }
                *(u16x8*)ldst_lane = tt;
            }
        };

        f32x4 acc[3][4] = {};
        bf16x8 af[2][3];

        stage(0, 0);
        loadW(co_wave, 0, af[0]);
        __syncthreads();

        #pragma unroll
        for (int s = 0; s < NSTEP; ++s) {
            const int cur = s & 1, nxt = cur ^ 1;
            if (s + 1 < NSTEP) {
                stage((s + 1) * 32, nxt);
                loadW(co_wave, (s + 1) * 32, af[nxt]);
            }
            bf16x8 bfr[4];
            #pragma unroll
            for (int nf = 0; nf < 4; ++nf) {
                const int pxr = nf * 16 + lr;
                const int kpp = lg ^ ((pxr >> 1) & 3);
                bfr[nf] = *(const bf16x8*)&Xt[cur][pxr * 32 + kpp * 8];
            }
            #pragma unroll
            for (int mf = 0; mf < 3; ++mf)
                #pragma unroll
                for (int nf = 0; nf < 4; ++nf)
                    acc[mf][nf] = __builtin_amdgcn_mfma_f32_16x16x32_bf16(
                        af[cur][mf], bfr[nf], acc[mf][nf], 0, 0, 0);
            __syncthreads();
        }

        const float* Rf = (const float*)Rv;
        const u16*   Rh = (const u16*)Rv;
        #pragma unroll
        for (int mf = 0; mf < 3; ++mf) {
            const int co_b = co_wave + mf * 16 + lg * 4;
            if (co_b >= CO) continue;
            #pragma unroll
            for (int nf = 0; nf < 4; ++nf) {
                const int pl = pix0 + nf * 16 + lr;
                const size_t pg = (size_t)p0 + nf * 16 + lr;
                float v[4];
                #pragma unroll
                for (int r = 0; r < 4; ++r) {
                    v[r] = acc[mf][nf][r] + bias[co_b + r];
                    if (RELU) v[r] = fmaxf(v[r], 0.f);
                }
                if (RES == 1) {
                    #pragma unroll
                    for (int r = 0; r < 4; ++r)
                        v[r] += Rf[((size_t)(b * CO + co_b + r)) * HWSZ + pl];
                }
                if (RES == 2) {
                    u16x4 rr = *(const u16x4*)&Rh[pg * 180 + co_b];
                    #pragma unroll
                    for (int r = 0; r < 4; ++r) v[r] += bf2f(rr[r]);
                }
                if (OUTM == 1) {
                    u16x4 o;
                    #pragma unroll
                    for (int r = 0; r < 4; ++r) o[r] = f2bf(v[r]);
                    *(u16x4*)&((u16*)Yv)[pg * OSTR + co_b] = o;
                } else {
                    #pragma unroll
                    for (int r = 0; r < 4; ++r)
                        ((float*)Yv)[((size_t)(b * CO + co_b + r)) * HWSZ + pl] = v[r];
                }
            }
        }
        if (t + 1 < TPB) __syncthreads();   // epilogue done before next stage
    }
}

// ---------------------------------------------------------------------------
// BN stats (verbatim r8)
// ---------------------------------------------------------------------------
__global__ __launch_bounds__(256) void bn_part(const u16* __restrict__ zt,
                                               float* __restrict__ part)
{
    const int tid = threadIdx.x;
    const int oc  = tid & 63;
    const int pp  = tid >> 6;
    if (oc >= 45) return;
    const int stripe = blockIdx.x * 4 + pp;
    const int pb = blockIdx.x * 1024 + pp;
    float s[8] = {}, q[8] = {};
    for (int i = 0; i < 256; ++i) {
        const int p = pb + i * 4;
        u16x8 t = *(const u16x8*)&zt[(size_t)p * 360 + oc * 8];
        #pragma unroll
        for (int j = 0; j < 8; ++j) {
            float v = bf2f(t[j]);
            s[j] += v; q[j] += v * v;
        }
    }
    float* pr = part + ((size_t)stripe * 45 + oc) * 16;
    #pragma unroll
    for (int j = 0; j < 8; ++j) { pr[j] = s[j]; pr[8 + j] = q[j]; }
}

__global__ __launch_bounds__(256) void bn_fin(const float* __restrict__ part,
                                              const float* __restrict__ g,
                                              const float* __restrict__ bb,
                                              float* __restrict__ sc,
                                              float* __restrict__ sh)
{
    const int oc = blockIdx.x;
    const int t  = threadIdx.x;
    const float* p1 = part + ((size_t)t * 45 + oc) * 16;
    const float* p2 = part + ((size_t)(t + 256) * 45 + oc) * 16;
    float v[16];
    #pragma unroll
    for (int k = 0; k < 16; ++k) v[k] = p1[k] + p2[k];
    #pragma unroll
    for (int k = 0; k < 16; ++k)
        for (int m = 32; m; m >>= 1) v[k] += __shfl_xor(v[k], m, 64);
    __shared__ float red[4][16];
    if ((t & 63) == 0) {
        #pragma unroll
        for (int k = 0; k < 16; ++k) red[t >> 6][k] = v[k];
    }
    __syncthreads();
    if (t == 0) {
        const float invN = 1.f / (float)NPIX;
        #pragma unroll
        for (int j = 0; j < 8; ++j) {
            const int c = oc * 8 + j;
            float su = red[0][j] + red[1][j] + red[2][j] + red[3][j];
            float sq = red[0][8+j] + red[1][8+j] + red[2][8+j] + red[3][8+j];
            float mean = su * invN;
            float var  = sq * invN - mean * mean;
            float istd = 1.f / sqrtf(var + 1e-5f);
            float s = g[c] * istd;
            sc[c] = s;
            sh[c] = bb[c] - mean * s;
        }
    }
}

// ---------------------------------------------------------------------------
// attn_v3 (verbatim r17)
// ---------------------------------------------------------------------------
template<int WS>
__global__ __launch_bounds__(256) void attn_v3(
    const u16* __restrict__ zt, const float* __restrict__ scale,
    const float* __restrict__ shiftc, u16* __restrict__ ot, int chunk)
{
    constexpr int NP  = WS * WS;
    constexpr int GPB = 256 / NP;
    constexpr int SH  = WS / 2;
    constexpr int NW  = 256 / WS;

    __shared__ float qs[256 * 12];
    __shared__ float vs[256 * 12];
    __shared__ float scs[120], shs[120];

    const int tid = threadIdx.x;
    if (tid < 120) {
        scs[tid] = scale[chunk * 120 + tid];
        shs[tid] = shiftc[chunk * 120 + tid];
    }

    const int lg  = tid / NP;
    const int n   = tid % NP;
    const int gidx = blockIdx.x * GPB + lg;

    const int head = gidx % 6;
    const int win  = gidx / 6;
    const int wcol = win % NW;
    const int tmp  = win / NW;
    const int wrow = tmp % NW;
    const int b    = tmp / NW;

    const int i = n / WS, j = n % WS;
    const int hh = (wrow * WS + i + SH) & 255;
    const int ww = (wcol * WS + j + SH) & 255;
    const size_t zrow = (size_t)((b << 16) | (hh << 8) | ww) * 360;

    const int cq = chunk * 120 + head * 10;
    const int cl = head * 10;

    u16x8u q8 = *(const u16x8u*)&zt[zrow + cq];
    u16x2  q2 = *(const u16x2*)&zt[zrow + cq + 8];
    u16x8u v8 = *(const u16x8u*)&zt[zrow + cq + 60];
    u16x2  v2 = *(const u16x2*)&zt[zrow + cq + 68];
    __syncthreads();

    float q[10];
    float* qrow = &qs[tid * 12];
    float* vrow = &vs[tid * 12];
    #pragma unroll
    for (int c = 0; c < 8; ++c) {
        q[c] = bf2f(q8[c]) * scs[cl + c] + shs[cl + c];
        qrow[c] = q[c];
        vrow[c] = bf2f(v8[c]) * scs[60 + cl + c] + shs[60 + cl + c];
    }
    q[8] = bf2f(q2[0]) * scs[cl + 8] + shs[cl + 8];
    q[9] = bf2f(q2[1]) * scs[cl + 9] + shs[cl + 9];
    qrow[8] = q[8]; qrow[9] = q[9];
    vrow[8] = bf2f(v2[0]) * scs[60 + cl + 8] + shs[60 + cl + 8];
    vrow[9] = bf2f(v2[1]) * scs[60 + cl + 9] + shs[60 + cl + 9];
    qrow[10] = 0.f; qrow[11] = 0.f;
    vrow[10] = 0.f; vrow[11] = 0.f;
    __syncthreads();

    const float* qg = &qs[(lg * NP) * 12];
    const float* vg = &vs[(lg * NP) * 12];

    float mx = -1e30f;
    for (int m = 0; m < NP; ++m) {
        f32x4 a0 = *(const f32x4*)&qg[m * 12];
        f32x4 a1 = *(const f32x4*)&qg[m * 12 + 4];
        f32x4 a2 = *(const f32x4*)&qg[m * 12 + 8];
        float d = q[0]*a0[0] + q[1]*a0[1] + q[2]*a0[2] + q[3]*a0[3]
                + q[4]*a1[0] + q[5]*a1[1] + q[6]*a1[2] + q[7]*a1[3]
                + q[8]*a2[0] + q[9]*a2[1];
        mx = fmaxf(mx, d);
    }
    float s = 0.f;
    float o[10] = {};
    for (int m = 0; m < NP; ++m) {
        f32x4 a0 = *(const f32x4*)&qg[m * 12];
        f32x4 a1 = *(const f32x4*)&qg[m * 12 + 4];
        f32x4 a2 = *(const f32x4*)&qg[m * 12 + 8];
        float d = q[0]*a0[0] + q[1]*a0[1] + q[2]*a0[2] + q[3]*a0[3]
                + q[4]*a1[0] + q[5]*a1[1] + q[6]*a1[2] + q[7]*a1[3]
                + q[8]*a2[0] + q[9]*a2[1];
        float e = __expf(d - mx);
        s += e;
        f32x4 b0 = *(const f32x4*)&vg[m * 12];
        f32x4 b1 = *(const f32x4*)&vg[m * 12 + 4];
        f32x4 b2 = *(const f32x4*)&vg[m * 12 + 8];
        o[0] += e * b0[0]; o[1] += e * b0[1]; o[2] += e * b0[2]; o[3] += e * b0[3];
        o[4] += e * b1[0]; o[5] += e * b1[1]; o[6] += e * b1[2]; o[7] += e * b1[3];
        o[8] += e * b2[0]; o[9] += e * b2[1];
    }
    const float inv = 1.f / s;
    u16* orow = ot + (size_t)((b << 16) | (hh << 8) | ww) * 180 + chunk * 60 + head * 10;
    u16x8u o8;
    #pragma unroll
    for (int c = 0; c < 8; ++c) o8[c] = f2bf(o[c] * inv);
    u16x2 o2;
    o2[0] = f2bf(o[8] * inv);
    o2[1] = f2bf(o[9] * inv);
    *(u16x8u*)&orow[0] = o8;
    *(u16x2*)&orow[8]  = o2;
}

// ---------------------------------------------------------------------------
extern "C" void kernel_launch(void* const* d_in, const int* in_sizes, int n_in,
                              void* d_out, int out_size, void* d_ws, size_t ws_size,
                              hipStream_t stream)
{
    const float* x     = (const float*)d_in[0];
    const float* w0    = (const float*)d_in[1];
    const float* b0    = (const float*)d_in[2];
    const float* w1    = (const float*)d_in[3];
    const float* b1    = (const float*)d_in[4];
    const float* w_in  = (const float*)d_in[5];
    const float* b_in  = (const float*)d_in[6];
    const float* bn_g  = (const float*)d_in[7];
    const float* bn_b  = (const float*)d_in[8];
    const float* w_out = (const float*)d_in[9];
    const float* b_out = (const float*)d_in[10];
    float* out = (float*)d_out;

    u16* y   = (u16*)d_ws;                      // [131072][360] (later zt)
    u16* x1b = y   + (size_t)NPIX * 360;        // [131072][180]
    u16* ot  = x1b + (size_t)NPIX * 180;        // [131072][180]
    u16* W0p = ot  + (size_t)NPIX * 180;        // 384x192
    u16* Wip = W0p + 384 * 192;                 // 384x192
    u16* W1p = Wip + 384 * 192;                 // 192x384
    u16* Wop = W1p + 192 * 384;                 // 192x192
    float* part   = (float*)(Wop + 192 * 192);  // 512*45*16
    float* scale  = part + 512 * 45 * 16;
    float* shiftc = scale + 360;
    u16* zt = y;

    dim3 blk(256);

    prep_w<<<dim3(288), blk, 0, stream>>>(w0, w1, w_in, w_out, W0p, W1p, Wip, Wop);

    // conv1 (v9, (2048,2) grid): y = relu(W0 @ shift(x) + b0)  -> y NHWC360
    conv_v9<180, 360, 36, 0, 0,   true,  0, 1, 360>
        <<<dim3(2048, 2), blk, 0, stream>>>(x, W0p, b0, nullptr, y);
    // conv2 (v10, 4 tiles/block): x1 = W1 @ shift(y) + b1 + x  -> x1b NHWC180
    conv_v10<360, 180, 72, 360, false, 1, 1, 180, false, 4>
        <<<dim3(512, 1), blk, 0, stream>>>(y, W1p, b1, x, x1b);
    // conv3 (v10, COSPLIT, 1 tile/block): z = W_in @ x1 + b_in -> zt NHWC360
    conv_v10<180, 360, 0,  180, false, 0, 1, 360, true, 1>
        <<<dim3(4096), blk, 0, stream>>>(x1b, Wip, b_in, nullptr, zt);
    // BN statistics
    bn_part<<<dim3(128), blk, 0, stream>>>(zt, part);
    bn_fin<<<dim3(45), blk, 0, stream>>>(part, bn_g, bn_b, scale, shiftc);
    // window attention -> ot NHWC180
    attn_v3<2><<<dim3(3072), blk, 0, stream>>>(zt, scale, shiftc, ot, 0);
    attn_v3<4><<<dim3(3072), blk, 0, stream>>>(zt, scale, shiftc, ot, 1);
    attn_v3<8><<<dim3(3072), blk, 0, stream>>>(zt, scale, shiftc, ot, 2);
    // conv4 (v10, 4 tiles/block): out = W_out @ ot + b_out + x1 -> fp32 NCHW
    conv_v10<180, 180, 0,  180, false, 2, 0, 0, false, 4>
        <<<dim3(512, 1), blk, 0, stream>>>(ot, Wop, b_out, x1b, out);
}

// Round 23
// 408.782 us; speedup vs baseline: 3.3836x; 3.3836x over previous
//
#include <hip/hip_runtime.h>
#include <hip/hip_bf16.h>

#define HWSZ 65536   // 256*256
#define NPIX 131072  // 2 * HWSZ

typedef unsigned short u16;
typedef __bf16 bf16x8 __attribute__((ext_vector_type(8)));
typedef float f32x4 __attribute__((ext_vector_type(4)));
typedef unsigned short u16x2 __attribute__((ext_vector_type(2)));
typedef unsigned short u16x4 __attribute__((ext_vector_type(4)));
typedef unsigned short u16x8 __attribute__((ext_vector_type(8)));
typedef unsigned short u16x8u __attribute__((ext_vector_type(8), aligned(4)));

__device__ inline u16 f2bf(float f) {
    unsigned int x = __builtin_bit_cast(unsigned int, f);
    unsigned int r = x + 0x7FFFu + ((x >> 16) & 1u);
    return (u16)(r >> 16);
}
__device__ inline float bf2f(u16 u) {
    unsigned int x = ((unsigned int)u) << 16;
    return __builtin_bit_cast(float, x);
}

// ---------------------------------------------------------------------------
// Weight prep (verbatim r5-r21)
// ---------------------------------------------------------------------------
__global__ __launch_bounds__(256) void prep_w(
    const float* __restrict__ w0, const float* __restrict__ w1,
    const float* __restrict__ wi, const float* __restrict__ wo,
    u16* __restrict__ W0p, u16* __restrict__ W1p,
    u16* __restrict__ Wip, u16* __restrict__ Wop)
{
    const int i = blockIdx.x * 256 + threadIdx.x;   // < 73728
    {
        const int r = i / 192, c = i % 192;
        const bool ok = (r < 360) && (c < 180);
        W0p[i] = ok ? f2bf(w0[r * 180 + c]) : (u16)0;
        Wip[i] = ok ? f2bf(wi[r * 180 + c]) : (u16)0;
    }
    {
        const int r = i / 384, c = i % 384;
        W1p[i] = (r < 180 && c < 360) ? f2bf(w1[r * 360 + c]) : (u16)0;
    }
    if (i < 36864) {
        const int r = i / 192, c = i % 192;
        Wop[i] = (r < 180 && c < 180) ? f2bf(wo[r * 180 + c]) : (u16)0;
    }
}

// ---------------------------------------------------------------------------
// conv_v9: reg-staging conv for conv1 (fp32 NCHW input).
// Non-COSPLIT: co-half from blockIdx.y ((N,2) grid — measured best, ~103 us).
// launch_bounds(256,4): the allocator's balanced point (60 VGPR, no spill).
// ---------------------------------------------------------------------------
template<int CI, int CO, int G, int INM, int XSTR, bool RELU, int RES, int OUTM, int OSTR, bool COSPLIT>
__global__ __launch_bounds__(256, 4) void conv_v9(
    const void* __restrict__ Xv, const u16* __restrict__ Wp,
    const float* __restrict__ bias, const void* __restrict__ Rv,
    void* __restrict__ Yv)
{
    constexpr int CI_PAD = ((CI + 31) / 32) * 32;
    constexpr int NSTEP  = CI_PAD / 32;
    constexpr int LDK    = 40;

    __shared__ u16 Xt[2][64 * LDK];

    const int tid = threadIdx.x;
    const int bid = blockIdx.x;
    int px_tile, co0;
    if (COSPLIT) {
        co0     = ((bid >> 3) & 1) * 192;
        px_tile = ((bid >> 4) << 3) | (bid & 7);
    } else {
        co0 = blockIdx.y * 192; px_tile = bid;
    }
    const int p0   = px_tile << 6;
    const int b    = p0 >> 16;
    const int pix0 = p0 & 65535;
    const int h    = pix0 >> 8;
    const int w0c  = pix0 & 255;
    const int lane = tid & 63, wid = tid >> 6;
    const int lr = lane & 15, lg = lane >> 4;
    const int co_wave = co0 + wid * 48;

    const float* Xf = (const float*)Xv + (size_t)b * CI * HWSZ;
    const u16*   Xh = (const u16*)Xv;

    const int xn  = tid & 63;
    const int k4a = tid >> 6;

    auto loadX = [&](int kt, u16x4 (&r)[2]) {
        #pragma unroll
        for (int it = 0; it < 2; ++it) {
            const int k4 = k4a + it * 4;
            const int c0 = kt + k4 * 4;
            u16x4 v = {0, 0, 0, 0};
            if (c0 < CI) {
                int dh = 0, dw = 0;
                if (G > 0) {
                    const int g = c0 / G;
                    if      (g == 0) dw = 1;
                    else if (g == 1) dw = -1;
                    else if (g == 2) dh = 1;
                    else if (g == 3) dh = -1;
                }
                const int hh = h + dh;
                const int wp = w0c + xn + dw;
                if (hh >= 0 && hh < 256 && wp >= 0 && wp < 256) {
                    if constexpr (INM == 1) {
                        v = *(const u16x4*)&Xh[(size_t)((b << 16) | (hh << 8) | wp) * XSTR + c0];
                    } else {
                        const float* xs = Xf + (size_t)c0 * HWSZ + hh * 256 + wp;
                        #pragma unroll
                        for (int j = 0; j < 4; ++j) v[j] = f2bf(xs[(size_t)j * HWSZ]);
                    }
                }
            }
            r[it] = v;
        }
    };

    auto loadW = [&](int kt, bf16x8 (&a)[3]) {
        #pragma unroll
        for (int mf = 0; mf < 3; ++mf)
            a[mf] = *(const bf16x8*)&Wp[(size_t)(co_wave + mf * 16 + lr) * CI_PAD + kt + lg * 8];
    };

    auto writeLDS = [&](u16x4 (&r)[2], int buf) {
        *(u16x4*)&Xt[buf][xn * LDK + k4a * 4]       = r[0];
        *(u16x4*)&Xt[buf][xn * LDK + (k4a + 4) * 4] = r[1];
    };

    f32x4 acc[3][4] = {};
    u16x4 raw[2][2];
    bf16x8 af[2][3];

    loadX(0, raw[0]);
    loadW(0, af[0]);
    writeLDS(raw[0], 0);

    #pragma unroll
    for (int s = 0; s < NSTEP; ++s) {
        const int cur = s & 1, nxt = cur ^ 1;
        __syncthreads();
        if (s + 1 < NSTEP) {
            loadX((s + 1) * 32, raw[nxt]);
            loadW((s + 1) * 32, af[nxt]);
        }
        bf16x8 bfr[4];
        #pragma unroll
        for (int nf = 0; nf < 4; ++nf)
            bfr[nf] = *(const bf16x8*)&Xt[cur][(nf * 16 + lr) * LDK + lg * 8];
        #pragma unroll
        for (int mf = 0; mf < 3; ++mf)
            #pragma unroll
            for (int nf = 0; nf < 4; ++nf)
                acc[mf][nf] = __builtin_amdgcn_mfma_f32_16x16x32_bf16(
                    af[cur][mf], bfr[nf], acc[mf][nf], 0, 0, 0);
        if (s + 1 < NSTEP) writeLDS(raw[nxt], nxt);
    }

    const float* Rf = (const float*)Rv;
    const u16*   Rh = (const u16*)Rv;
    #pragma unroll
    for (int mf = 0; mf < 3; ++mf) {
        const int co_b = co_wave + mf * 16 + lg * 4;
        if (co_b >= CO) continue;
        #pragma unroll
        for (int nf = 0; nf < 4; ++nf) {
            const int pl = pix0 + nf * 16 + lr;
            const size_t pg = (size_t)p0 + nf * 16 + lr;
            float v[4];
            #pragma unroll
            for (int r = 0; r < 4; ++r) {
                v[r] = acc[mf][nf][r] + bias[co_b + r];
                if (RELU) v[r] = fmaxf(v[r], 0.f);
            }
            if (RES == 1) {
                #pragma unroll
                for (int r = 0; r < 4; ++r)
                    v[r] += Rf[((size_t)(b * CO + co_b + r)) * HWSZ + pl];
            }
            if (RES == 2) {
                u16x4 rr = *(const u16x4*)&Rh[pg * 180 + co_b];
                #pragma unroll
                for (int r = 0; r < 4; ++r) v[r] += bf2f(rr[r]);
            }
            if (OUTM == 1) {
                u16x4 o;
                #pragma unroll
                for (int r = 0; r < 4; ++r) o[r] = f2bf(v[r]);
                *(u16x4*)&((u16*)Yv)[pg * OSTR + co_b] = o;
            } else {
                #pragma unroll
                for (int r = 0; r < 4; ++r)
                    ((float*)Yv)[((size_t)(b * CO + co_b + r)) * HWSZ + pl] = v[r];
            }
        }
    }
}

// ---------------------------------------------------------------------------
// conv_v10 (verbatim r21): global_load_lds staging conv (NHWC bf16 input).
// ---------------------------------------------------------------------------
template<int CI, int CO, int G, int XSTR, bool RELU, int RES, int OUTM, int OSTR, bool COSPLIT>
__global__ __launch_bounds__(256) void conv_v10(
    const u16* __restrict__ Xh, const u16* __restrict__ Wp,
    const float* __restrict__ bias, const void* __restrict__ Rv,
    void* __restrict__ Yv)
{
    constexpr int CI_PAD = ((CI + 31) / 32) * 32;
    constexpr int NSTEP  = CI_PAD / 32;

    __shared__ u16 Xt[2][256 * 8];   // 2 x 4 KB

    const int tid = threadIdx.x;
    const int bid = blockIdx.x;
    int px_tile, co0;
    if (COSPLIT) {
        co0     = ((bid >> 3) & 1) * 192;
        px_tile = ((bid >> 4) << 3) | (bid & 7);
    } else {
        co0 = blockIdx.y * 192; px_tile = bid;
    }
    const int p0   = px_tile << 6;
    const int b    = p0 >> 16;
    const int pix0 = p0 & 65535;
    const int h    = pix0 >> 8;
    const int w0c  = pix0 & 255;
    const int lane = tid & 63, wid = tid >> 6;
    const int lr = lane & 15, lg = lane >> 4;
    const int co_wave = co0 + wid * 48;

    const int sg  = (wid << 6) | lane;
    const int spx = sg >> 2;
    const int khp = sg & 3;
    const int kh  = khp ^ ((spx >> 1) & 3);

    auto stage = [&](int kt, int buf) {
        const int c0 = kt + kh * 8;
        u16* ldst_lane = &Xt[buf][sg * 8];
        int dh = 0, dw = 0; bool uni = true;
        if (G > 0) {
            const int g0 = c0 / G;
            uni = (g0 == (c0 + 7) / G);
            if      (g0 == 0) dw = 1;
            else if (g0 == 1) dw = -1;
            else if (g0 == 2) dh = 1;
            else if (g0 == 3) dh = -1;
        }
        const int hh = h + dh, wp = w0c + spx + dw;
        const bool pxok = (hh >= 0 && hh < 256 && wp >= 0 && wp < 256);
        if (c0 < CI && uni && pxok) {
            const u16* src = &Xh[(size_t)((b << 16) | (hh << 8) | wp) * XSTR + c0];
            u16* wbase = &Xt[buf][(wid << 6) * 8];
            __builtin_amdgcn_global_load_lds(
                (const __attribute__((address_space(1))) unsigned int*)src,
                (__attribute__((address_space(3))) unsigned int*)wbase, 16, 0, 0);
        } else {
            u16x8 t = {0, 0, 0, 0, 0, 0, 0, 0};
            if (c0 < CI && pxok) {
                #pragma unroll
                for (int j = 0; j < 8; ++j) {
                    const int c = c0 + j;
                    if (c < CI) {
                        int dh2 = 0, dw2 = 0;
                        if (G > 0) {
                            const int g = c / G;
                            if      (g == 0) dw2 = 1;
                            else if (g == 1) dw2 = -1;
                            else if (g == 2) dh2 = 1;
                            else if (g == 3) dh2 = -1;
                        }
                        const int h2 = h + dh2, w2 = w0c + spx + dw2;
                        if (h2 >= 0 && h2 < 256 && w2 >= 0 && w2 < 256)
                            t[j] = Xh[(size_t)((b << 16) | (h2 << 8) | w2) * XSTR + c];
                    }
                }
            }
            *(u16x8*)ldst_lane = t;
        }
    };

    auto loadW = [&](int kt, bf16x8 (&a)[3]) {
        #pragma unroll
        for (int mf = 0; mf < 3; ++mf)
            a[mf] = *(const bf16x8*)&Wp[(size_t)(co_wave + mf * 16 + lr) * CI_PAD + kt + lg * 8];
    };

    f32x4 acc[3][4] = {};
    bf16x8 af[2][3];

    stage(0, 0);
    loadW(0, af[0]);
    __syncthreads();

    #pragma unroll
    for (int s = 0; s < NSTEP; ++s) {
        const int cur = s & 1, nxt = cur ^ 1;
        if (s + 1 < NSTEP) {
            stage((s + 1) * 32, nxt);
            loadW((s + 1) * 32, af[nxt]);
        }
        bf16x8 bfr[4];
        #pragma unroll
        for (int nf = 0; nf < 4; ++nf) {
            const int pxr = nf * 16 + lr;
            const int kpp = lg ^ ((pxr >> 1) & 3);
            bfr[nf] = *(const bf16x8*)&Xt[cur][pxr * 32 + kpp * 8];
        }
        #pragma unroll
        for (int mf = 0; mf < 3; ++mf)
            #pragma unroll
            for (int nf = 0; nf < 4; ++nf)
                acc[mf][nf] = __builtin_amdgcn_mfma_f32_16x16x32_bf16(
                    af[cur][mf], bfr[nf], acc[mf][nf], 0, 0, 0);
        __syncthreads();
    }

    const float* Rf = (const float*)Rv;
    const u16*   Rh = (const u16*)Rv;
    #pragma unroll
    for (int mf = 0; mf < 3; ++mf) {
        const int co_b = co_wave + mf * 16 + lg * 4;
        if (co_b >= CO) continue;
        #pragma unroll
        for (int nf = 0; nf < 4; ++nf) {
            const int pl = pix0 + nf * 16 + lr;
            const size_t pg = (size_t)p0 + nf * 16 + lr;
            float v[4];
            #pragma unroll
            for (int r = 0; r < 4; ++r) {
                v[r] = acc[mf][nf][r] + bias[co_b + r];
                if (RELU) v[r] = fmaxf(v[r], 0.f);
            }
            if (RES == 1) {
                #pragma unroll
                for (int r = 0; r < 4; ++r)
                    v[r] += Rf[((size_t)(b * CO + co_b + r)) * HWSZ + pl];
            }
            if (RES == 2) {
                u16x4 rr = *(const u16x4*)&Rh[pg * 180 + co_b];
                #pragma unroll
                for (int r = 0; r < 4; ++r) v[r] += bf2f(rr[r]);
            }
            if (OUTM == 1) {
                u16x4 o;
                #pragma unroll
                for (int r = 0; r < 4; ++r) o[r] = f2bf(v[r]);
                *(u16x4*)&((u16*)Yv)[pg * OSTR + co_b] = o;
            } else {
                #pragma unroll
                for (int r = 0; r < 4; ++r)
                    ((float*)Yv)[((size_t)(b * CO + co_b + r)) * HWSZ + pl] = v[r];
            }
        }
    }
}

// ---------------------------------------------------------------------------
// BN stats (verbatim r8)
// ---------------------------------------------------------------------------
__global__ __launch_bounds__(256) void bn_part(const u16* __restrict__ zt,
                                               float* __restrict__ part)
{
    const int tid = threadIdx.x;
    const int oc  = tid & 63;
    const int pp  = tid >> 6;
    if (oc >= 45) return;
    const int stripe = blockIdx.x * 4 + pp;
    const int pb = blockIdx.x * 1024 + pp;
    float s[8] = {}, q[8] = {};
    for (int i = 0; i < 256; ++i) {
        const int p = pb + i * 4;
        u16x8 t = *(const u16x8*)&zt[(size_t)p * 360 + oc * 8];
        #pragma unroll
        for (int j = 0; j < 8; ++j) {
            float v = bf2f(t[j]);
            s[j] += v; q[j] += v * v;
        }
    }
    float* pr = part + ((size_t)stripe * 45 + oc) * 16;
    #pragma unroll
    for (int j = 0; j < 8; ++j) { pr[j] = s[j]; pr[8 + j] = q[j]; }
}

__global__ __launch_bounds__(256) void bn_fin(const float* __restrict__ part,
                                              const float* __restrict__ g,
                                              const float* __restrict__ bb,
                                              float* __restrict__ sc,
                                              float* __restrict__ sh)
{
    const int oc = blockIdx.x;
    const int t  = threadIdx.x;
    const float* p1 = part + ((size_t)t * 45 + oc) * 16;
    const float* p2 = part + ((size_t)(t + 256) * 45 + oc) * 16;
    float v[16];
    #pragma unroll
    for (int k = 0; k < 16; ++k) v[k] = p1[k] + p2[k];
    #pragma unroll
    for (int k = 0; k < 16; ++k)
        for (int m = 32; m; m >>= 1) v[k] += __shfl_xor(v[k], m, 64);
    __shared__ float red[4][16];
    if ((t & 63) == 0) {
        #pragma unroll
        for (int k = 0; k < 16; ++k) red[t >> 6][k] = v[k];
    }
    __syncthreads();
    if (t == 0) {
        const float invN = 1.f / (float)NPIX;
        #pragma unroll
        for (int j = 0; j < 8; ++j) {
            const int c = oc * 8 + j;
            float su = red[0][j] + red[1][j] + red[2][j] + red[3][j];
            float sq = red[0][8+j] + red[1][8+j] + red[2][8+j] + red[3][8+j];
            float mean = su * invN;
            float var  = sq * invN - mean * mean;
            float istd = 1.f / sqrtf(var + 1e-5f);
            float s = g[c] * istd;
            sc[c] = s;
            sh[c] = bb[c] - mean * s;
        }
    }
}

// ---------------------------------------------------------------------------
// attn_v3 (verbatim r17)
// ---------------------------------------------------------------------------
template<int WS>
__global__ __launch_bounds__(256) void attn_v3(
    const u16* __restrict__ zt, const float* __restrict__ scale,
    const float* __restrict__ shiftc, u16* __restrict__ ot, int chunk)
{
    constexpr int NP  = WS * WS;
    constexpr int GPB = 256 / NP;
    constexpr int SH  = WS / 2;
    constexpr int NW  = 256 / WS;

    __shared__ float qs[256 * 12];
    __shared__ float vs[256 * 12];
    __shared__ float scs[120], shs[120];

    const int tid = threadIdx.x;
    if (tid < 120) {
        scs[tid] = scale[chunk * 120 + tid];
        shs[tid] = shiftc[chunk * 120 + tid];
    }

    const int lg  = tid / NP;
    const int n   = tid % NP;
    const int gidx = blockIdx.x * GPB + lg;

    const int head = gidx % 6;
    const int win  = gidx / 6;
    const int wcol = win % NW;
    const int tmp  = win / NW;
    const int wrow = tmp % NW;
    const int b    = tmp / NW;

    const int i = n / WS, j = n % WS;
    const int hh = (wrow * WS + i + SH) & 255;
    const int ww = (wcol * WS + j + SH) & 255;
    const size_t zrow = (size_t)((b << 16) | (hh << 8) | ww) * 360;

    const int cq = chunk * 120 + head * 10;
    const int cl = head * 10;

    u16x8u q8 = *(const u16x8u*)&zt[zrow + cq];
    u16x2  q2 = *(const u16x2*)&zt[zrow + cq + 8];
    u16x8u v8 = *(const u16x8u*)&zt[zrow + cq + 60];
    u16x2  v2 = *(const u16x2*)&zt[zrow + cq + 68];
    __syncthreads();

    float q[10];
    float* qrow = &qs[tid * 12];
    float* vrow = &vs[tid * 12];
    #pragma unroll
    for (int c = 0; c < 8; ++c) {
        q[c] = bf2f(q8[c]) * scs[cl + c] + shs[cl + c];
        qrow[c] = q[c];
        vrow[c] = bf2f(v8[c]) * scs[60 + cl + c] + shs[60 + cl + c];
    }
    q[8] = bf2f(q2[0]) * scs[cl + 8] + shs[cl + 8];
    q[9] = bf2f(q2[1]) * scs[cl + 9] + shs[cl + 9];
    qrow[8] = q[8]; qrow[9] = q[9];
    vrow[8] = bf2f(v2[0]) * scs[60 + cl + 8] + shs[60 + cl + 8];
    vrow[9] = bf2f(v2[1]) * scs[60 + cl + 9] + shs[60 + cl + 9];
    qrow[10] = 0.f; qrow[11] = 0.f;
    vrow[10] = 0.f; vrow[11] = 0.f;
    __syncthreads();

    const float* qg = &qs[(lg * NP) * 12];
    const float* vg = &vs[(lg * NP) * 12];

    float mx = -1e30f;
    for (int m = 0; m < NP; ++m) {
        f32x4 a0 = *(const f32x4*)&qg[m * 12];
        f32x4 a1 = *(const f32x4*)&qg[m * 12 + 4];
        f32x4 a2 = *(const f32x4*)&qg[m * 12 + 8];
        float d = q[0]*a0[0] + q[1]*a0[1] + q[2]*a0[2] + q[3]*a0[3]
                + q[4]*a1[0] + q[5]*a1[1] + q[6]*a1[2] + q[7]*a1[3]
                + q[8]*a2[0] + q[9]*a2[1];
        mx = fmaxf(mx, d);
    }
    float s = 0.f;
    float o[10] = {};
    for (int m = 0; m < NP; ++m) {
        f32x4 a0 = *(const f32x4*)&qg[m * 12];
        f32x4 a1 = *(const f32x4*)&qg[m * 12 + 4];
        f32x4 a2 = *(const f32x4*)&qg[m * 12 + 8];
        float d = q[0]*a0[0] + q[1]*a0[1] + q[2]*a0[2] + q[3]*a0[3]
                + q[4]*a1[0] + q[5]*a1[1] + q[6]*a1[2] + q[7]*a1[3]
                + q[8]*a2[0] + q[9]*a2[1];
        float e = __expf(d - mx);
        s += e;
        f32x4 b0 = *(const f32x4*)&vg[m * 12];
        f32x4 b1 = *(const f32x4*)&vg[m * 12 + 4];
        f32x4 b2 = *(const f32x4*)&vg[m * 12 + 8];
        o[0] += e * b0[0]; o[1] += e * b0[1]; o[2] += e * b0[2]; o[3] += e * b0[3];
        o[4] += e * b1[0]; o[5] += e * b1[1]; o[6] += e * b1[2]; o[7] += e * b1[3];
        o[8] += e * b2[0]; o[9] += e * b2[1];
    }
    const float inv = 1.f / s;
    u16* orow = ot + (size_t)((b << 16) | (hh << 8) | ww) * 180 + chunk * 60 + head * 10;
    u16x8u o8;
    #pragma unroll
    for (int c = 0; c < 8; ++c) o8[c] = f2bf(o[c] * inv);
    u16x2 o2;
    o2[0] = f2bf(o[8] * inv);
    o2[1] = f2bf(o[9] * inv);
    *(u16x8u*)&orow[0] = o8;
    *(u16x2*)&orow[8]  = o2;
}

// ---------------------------------------------------------------------------
extern "C" void kernel_launch(void* const* d_in, const int* in_sizes, int n_in,
                              void* d_out, int out_size, void* d_ws, size_t ws_size,
                              hipStream_t stream)
{
    const float* x     = (const float*)d_in[0];
    const float* w0    = (const float*)d_in[1];
    const float* b0    = (const float*)d_in[2];
    const float* w1    = (const float*)d_in[3];
    const float* b1    = (const float*)d_in[4];
    const float* w_in  = (const float*)d_in[5];
    const float* b_in  = (const float*)d_in[6];
    const float* bn_g  = (const float*)d_in[7];
    const float* bn_b  = (const float*)d_in[8];
    const float* w_out = (const float*)d_in[9];
    const float* b_out = (const float*)d_in[10];
    float* out = (float*)d_out;

    u16* y   = (u16*)d_ws;                      // [131072][360] (later zt)
    u16* x1b = y   + (size_t)NPIX * 360;        // [131072][180]
    u16* ot  = x1b + (size_t)NPIX * 180;        // [131072][180]
    u16* W0p = ot  + (size_t)NPIX * 180;        // 384x192
    u16* Wip = W0p + 384 * 192;                 // 384x192
    u16* W1p = Wip + 384 * 192;                 // 192x384
    u16* Wop = W1p + 192 * 384;                 // 192x192
    float* part   = (float*)(Wop + 192 * 192);  // 512*45*16
    float* scale  = part + 512 * 45 * 16;
    float* shiftc = scale + 360;
    u16* zt = y;

    dim3 blk(256);

    prep_w<<<dim3(288), blk, 0, stream>>>(w0, w1, w_in, w_out, W0p, W1p, Wip, Wop);

    // conv1 (v9, (2048,2) grid — measured best): y = relu(W0 @ shift(x) + b0)
    conv_v9<180, 360, 36, 0, 0,   true,  0, 1, 360, false>
        <<<dim3(2048, 2), blk, 0, stream>>>(x, W0p, b0, nullptr, y);
    // conv2 (v10): x1 = W1 @ shift(y) + b1 + x                 -> x1b NHWC180
    conv_v10<360, 180, 72, 360, false, 1, 1, 180, false>
        <<<dim3(2048, 1), blk, 0, stream>>>(y, W1p, b1, x, x1b);
    // conv3 (v10, COSPLIT — r17 variant): z = W_in @ x1 + b_in -> zt NHWC360
    conv_v10<180, 360, 0,  180, false, 0, 1, 360, true>
        <<<dim3(4096), blk, 0, stream>>>(x1b, Wip, b_in, nullptr, zt);
    // BN statistics
    bn_part<<<dim3(128), blk, 0, stream>>>(zt, part);
    bn_fin<<<dim3(45), blk, 0, stream>>>(part, bn_g, bn_b, scale, shiftc);
    // window attention -> ot NHWC180
    attn_v3<2><<<dim3(3072), blk, 0, stream>>>(zt, scale, shiftc, ot, 0);
    attn_v3<4><<<dim3(3072), blk, 0, stream>>>(zt, scale, shiftc, ot, 1);
    attn_v3<8><<<dim3(3072), blk, 0, stream>>>(zt, scale, shiftc, ot, 2);
    // conv4 (v10): out = W_out @ ot + b_out + x1               -> out fp32 NCHW
    conv_v10<180, 180, 0,  180, false, 2, 0, 0, false>
        <<<dim3(2048, 1), blk, 0, stream>>>(ot, Wop, b_out, x1b, out);
}

// Round 24
// 398.487 us; speedup vs baseline: 3.4710x; 1.0258x over previous
//
#include <hip/hip_runtime.h>
#include <hip/hip_bf16.h>

#define HWSZ 65536   // 256*256
#define NPIX 131072  // 2 * HWSZ

typedef unsigned short u16;
typedef __bf16 bf16x8 __attribute__((ext_vector_type(8)));
typedef float f32x4 __attribute__((ext_vector_type(4)));
typedef unsigned short u16x2 __attribute__((ext_vector_type(2)));
typedef unsigned short u16x4 __attribute__((ext_vector_type(4)));
typedef unsigned short u16x8 __attribute__((ext_vector_type(8)));
typedef unsigned short u16x8u __attribute__((ext_vector_type(8), aligned(4)));

__device__ inline u16 f2bf(float f) {
    unsigned int x = __builtin_bit_cast(unsigned int, f);
    unsigned int r = x + 0x7FFFu + ((x >> 16) & 1u);
    return (u16)(r >> 16);
}
__device__ inline float bf2f(u16 u) {
    unsigned int x = ((unsigned int)u) << 16;
    return __builtin_bit_cast(float, x);
}

// ---------------------------------------------------------------------------
// Weight prep (verbatim r5-r23)
// ---------------------------------------------------------------------------
__global__ __launch_bounds__(256) void prep_w(
    const float* __restrict__ w0, const float* __restrict__ w1,
    const float* __restrict__ wi, const float* __restrict__ wo,
    u16* __restrict__ W0p, u16* __restrict__ W1p,
    u16* __restrict__ Wip, u16* __restrict__ Wop)
{
    const int i = blockIdx.x * 256 + threadIdx.x;   // < 73728
    {
        const int r = i / 192, c = i % 192;
        const bool ok = (r < 360) && (c < 180);
        W0p[i] = ok ? f2bf(w0[r * 180 + c]) : (u16)0;
        Wip[i] = ok ? f2bf(wi[r * 180 + c]) : (u16)0;
    }
    {
        const int r = i / 384, c = i % 384;
        W1p[i] = (r < 180 && c < 360) ? f2bf(w1[r * 360 + c]) : (u16)0;
    }
    if (i < 36864) {
        const int r = i / 192, c = i % 192;
        Wop[i] = (r < 180 && c < 180) ? f2bf(wo[r * 180 + c]) : (u16)0;
    }
}

// ---------------------------------------------------------------------------
// conv_v14: 8-wave (512-thread) full-M conv for CO=360 (padded 384).
// One block = ALL co rows x 64 px; X staged ONCE per K-step (reg->LDS,
// double-buffered, one barrier/step); W frags depth-1 from L2.
// INM: 0 = fp32 NCHW input (fused transpose), 1 = bf16 NHWC stride XSTR.
// Output: bf16 NHWC stride 360. RELU optional. No residual needed here.
// ---------------------------------------------------------------------------
template<int CI, int G, int INM, int XSTR, bool RELU>
__global__ __launch_bounds__(512) void conv_v14(
    const void* __restrict__ Xv, const u16* __restrict__ Wp,
    const float* __restrict__ bias, u16* __restrict__ Yh)
{
    constexpr int CI_PAD = ((CI + 31) / 32) * 32;
    constexpr int NSTEP  = CI_PAD / 32;
    constexpr int LDK    = 40;

    __shared__ u16 Xt[2][64 * LDK];   // 2 x 5120 B

    const int tid = threadIdx.x;
    const int p0   = blockIdx.x << 6;
    const int b    = p0 >> 16;
    const int pix0 = p0 & 65535;
    const int h    = pix0 >> 8;
    const int w0c  = pix0 & 255;
    const int lane = tid & 63, wid = tid >> 6;   // wid 0..7
    const int lr = lane & 15, lg = lane >> 4;
    const int co_wave = wid * 48;                 // 0..336

    const float* Xf = (const float*)Xv + (size_t)b * CI * HWSZ;
    const u16*   Xh = (const u16*)Xv;

    const int xn  = tid & 63;    // pixel this thread stages
    const int k4a = tid >> 6;    // k-quad 0..7 (32 ch / 4)

    auto loadX = [&](int kt, u16x4& r) {
        const int c0 = kt + k4a * 4;
        u16x4 v = {0, 0, 0, 0};
        if (c0 < CI) {
            int dh = 0, dw = 0;
            if (G > 0) {                    // 4|G: quad shift-uniform
                const int g = c0 / G;
                if      (g == 0) dw = 1;
                else if (g == 1) dw = -1;
                else if (g == 2) dh = 1;
                else if (g == 3) dh = -1;
            }
            const int hh = h + dh;
            const int wp = w0c + xn + dw;
            if (hh >= 0 && hh < 256 && wp >= 0 && wp < 256) {
                if constexpr (INM == 1) {
                    v = *(const u16x4*)&Xh[(size_t)((b << 16) | (hh << 8) | wp) * XSTR + c0];
                } else {
                    const float* xs = Xf + (size_t)c0 * HWSZ + hh * 256 + wp;
                    #pragma unroll
                    for (int j = 0; j < 4; ++j) v[j] = f2bf(xs[(size_t)j * HWSZ]);
                }
            }
        }
        r = v;
    };

    auto loadW = [&](int kt, bf16x8 (&a)[3]) {
        #pragma unroll
        for (int mf = 0; mf < 3; ++mf)
            a[mf] = *(const bf16x8*)&Wp[(size_t)(co_wave + mf * 16 + lr) * CI_PAD + kt + lg * 8];
    };

    auto writeLDS = [&](u16x4& r, int buf) {
        *(u16x4*)&Xt[buf][xn * LDK + k4a * 4] = r;
    };

    f32x4 acc[3][4] = {};
    u16x4 raw[2];
    bf16x8 af[2][3];

    loadX(0, raw[0]);
    loadW(0, af[0]);
    writeLDS(raw[0], 0);

    #pragma unroll
    for (int s = 0; s < NSTEP; ++s) {
        const int cur = s & 1, nxt = cur ^ 1;
        __syncthreads();                      // Xt[cur] ready for all 8 waves
        if (s + 1 < NSTEP) {
            loadX((s + 1) * 32, raw[nxt]);
            loadW((s + 1) * 32, af[nxt]);
        }
        bf16x8 bfr[4];
        #pragma unroll
        for (int nf = 0; nf < 4; ++nf)
            bfr[nf] = *(const bf16x8*)&Xt[cur][(nf * 16 + lr) * LDK + lg * 8];
        #pragma unroll
        for (int mf = 0; mf < 3; ++mf)
            #pragma unroll
            for (int nf = 0; nf < 4; ++nf)
                acc[mf][nf] = __builtin_amdgcn_mfma_f32_16x16x32_bf16(
                    af[cur][mf], bfr[nf], acc[mf][nf], 0, 0, 0);
        if (s + 1 < NSTEP) writeLDS(raw[nxt], nxt);
    }

    // epilogue: co = co_wave + mf*16 + lg*4 + r, pixel = p0 + nf*16 + lr
    #pragma unroll
    for (int mf = 0; mf < 3; ++mf) {
        const int co_b = co_wave + mf * 16 + lg * 4;
        if (co_b >= 360) continue;
        #pragma unroll
        for (int nf = 0; nf < 4; ++nf) {
            const size_t pg = (size_t)p0 + nf * 16 + lr;
            u16x4 o;
            #pragma unroll
            for (int r = 0; r < 4; ++r) {
                float v = acc[mf][nf][r] + bias[co_b + r];
                if (RELU) v = fmaxf(v, 0.f);
                o[r] = f2bf(v);
            }
            *(u16x4*)&Yh[pg * 360 + co_b] = o;
        }
    }
}

// ---------------------------------------------------------------------------
// conv_v10 (verbatim r23): global_load_lds staging conv (NHWC bf16 input).
// ---------------------------------------------------------------------------
template<int CI, int CO, int G, int XSTR, bool RELU, int RES, int OUTM, int OSTR, bool COSPLIT>
__global__ __launch_bounds__(256) void conv_v10(
    const u16* __restrict__ Xh, const u16* __restrict__ Wp,
    const float* __restrict__ bias, const void* __restrict__ Rv,
    void* __restrict__ Yv)
{
    constexpr int CI_PAD = ((CI + 31) / 32) * 32;
    constexpr int NSTEP  = CI_PAD / 32;

    __shared__ u16 Xt[2][256 * 8];   // 2 x 4 KB

    const int tid = threadIdx.x;
    const int bid = blockIdx.x;
    int px_tile, co0;
    if (COSPLIT) {
        co0     = ((bid >> 3) & 1) * 192;
        px_tile = ((bid >> 4) << 3) | (bid & 7);
    } else {
        co0 = blockIdx.y * 192; px_tile = bid;
    }
    const int p0   = px_tile << 6;
    const int b    = p0 >> 16;
    const int pix0 = p0 & 65535;
    const int h    = pix0 >> 8;
    const int w0c  = pix0 & 255;
    const int lane = tid & 63, wid = tid >> 6;
    const int lr = lane & 15, lg = lane >> 4;
    const int co_wave = co0 + wid * 48;

    const int sg  = (wid << 6) | lane;
    const int spx = sg >> 2;
    const int khp = sg & 3;
    const int kh  = khp ^ ((spx >> 1) & 3);

    auto stage = [&](int kt, int buf) {
        const int c0 = kt + kh * 8;
        u16* ldst_lane = &Xt[buf][sg * 8];
        int dh = 0, dw = 0; bool uni = true;
        if (G > 0) {
            const int g0 = c0 / G;
            uni = (g0 == (c0 + 7) / G);
            if      (g0 == 0) dw = 1;
            else if (g0 == 1) dw = -1;
            else if (g0 == 2) dh = 1;
            else if (g0 == 3) dh = -1;
        }
        const int hh = h + dh, wp = w0c + spx + dw;
        const bool pxok = (hh >= 0 && hh < 256 && wp >= 0 && wp < 256);
        if (c0 < CI && uni && pxok) {
            const u16* src = &Xh[(size_t)((b << 16) | (hh << 8) | wp) * XSTR + c0];
            u16* wbase = &Xt[buf][(wid << 6) * 8];
            __builtin_amdgcn_global_load_lds(
                (const __attribute__((address_space(1))) unsigned int*)src,
                (__attribute__((address_space(3))) unsigned int*)wbase, 16, 0, 0);
        } else {
            u16x8 t = {0, 0, 0, 0, 0, 0, 0, 0};
            if (c0 < CI && pxok) {
                #pragma unroll
                for (int j = 0; j < 8; ++j) {
                    const int c = c0 + j;
                    if (c < CI) {
                        int dh2 = 0, dw2 = 0;
                        if (G > 0) {
                            const int g = c / G;
                            if      (g == 0) dw2 = 1;
                            else if (g == 1) dw2 = -1;
                            else if (g == 2) dh2 = 1;
                            else if (g == 3) dh2 = -1;
                        }
                        const int h2 = h + dh2, w2 = w0c + spx + dw2;
                        if (h2 >= 0 && h2 < 256 && w2 >= 0 && w2 < 256)
                            t[j] = Xh[(size_t)((b << 16) | (h2 << 8) | w2) * XSTR + c];
                    }
                }
            }
            *(u16x8*)ldst_lane = t;
        }
    };

    auto loadW = [&](int kt, bf16x8 (&a)[3]) {
        #pragma unroll
        for (int mf = 0; mf < 3; ++mf)
            a[mf] = *(const bf16x8*)&Wp[(size_t)(co_wave + mf * 16 + lr) * CI_PAD + kt + lg * 8];
    };

    f32x4 acc[3][4] = {};
    bf16x8 af[2][3];

    stage(0, 0);
    loadW(0, af[0]);
    __syncthreads();

    #pragma unroll
    for (int s = 0; s < NSTEP; ++s) {
        const int cur = s & 1, nxt = cur ^ 1;
        if (s + 1 < NSTEP) {
            stage((s + 1) * 32, nxt);
            loadW((s + 1) * 32, af[nxt]);
        }
        bf16x8 bfr[4];
        #pragma unroll
        for (int nf = 0; nf < 4; ++nf) {
            const int pxr = nf * 16 + lr;
            const int kpp = lg ^ ((pxr >> 1) & 3);
            bfr[nf] = *(const bf16x8*)&Xt[cur][pxr * 32 + kpp * 8];
        }
        #pragma unroll
        for (int mf = 0; mf < 3; ++mf)
            #pragma unroll
            for (int nf = 0; nf < 4; ++nf)
                acc[mf][nf] = __builtin_amdgcn_mfma_f32_16x16x32_bf16(
                    af[cur][mf], bfr[nf], acc[mf][nf], 0, 0, 0);
        __syncthreads();
    }

    const float* Rf = (const float*)Rv;
    const u16*   Rh = (const u16*)Rv;
    #pragma unroll
    for (int mf = 0; mf < 3; ++mf) {
        const int co_b = co_wave + mf * 16 + lg * 4;
        if (co_b >= CO) continue;
        #pragma unroll
        for (int nf = 0; nf < 4; ++nf) {
            const int pl = pix0 + nf * 16 + lr;
            const size_t pg = (size_t)p0 + nf * 16 + lr;
            float v[4];
            #pragma unroll
            for (int r = 0; r < 4; ++r) {
                v[r] = acc[mf][nf][r] + bias[co_b + r];
                if (RELU) v[r] = fmaxf(v[r], 0.f);
            }
            if (RES == 1) {
                #pragma unroll
                for (int r = 0; r < 4; ++r)
                    v[r] += Rf[((size_t)(b * CO + co_b + r)) * HWSZ + pl];
            }
            if (RES == 2) {
                u16x4 rr = *(const u16x4*)&Rh[pg * 180 + co_b];
                #pragma unroll
                for (int r = 0; r < 4; ++r) v[r] += bf2f(rr[r]);
            }
            if (OUTM == 1) {
                u16x4 o;
                #pragma unroll
                for (int r = 0; r < 4; ++r) o[r] = f2bf(v[r]);
                *(u16x4*)&((u16*)Yv)[pg * OSTR + co_b] = o;
            } else {
                #pragma unroll
                for (int r = 0; r < 4; ++r)
                    ((float*)Yv)[((size_t)(b * CO + co_b + r)) * HWSZ + pl] = v[r];
            }
        }
    }
}

// ---------------------------------------------------------------------------
// BN stats (verbatim r8)
// ---------------------------------------------------------------------------
__global__ __launch_bounds__(256) void bn_part(const u16* __restrict__ zt,
                                               float* __restrict__ part)
{
    const int tid = threadIdx.x;
    const int oc  = tid & 63;
    const int pp  = tid >> 6;
    if (oc >= 45) return;
    const int stripe = blockIdx.x * 4 + pp;
    const int pb = blockIdx.x * 1024 + pp;
    float s[8] = {}, q[8] = {};
    for (int i = 0; i < 256; ++i) {
        const int p = pb + i * 4;
        u16x8 t = *(const u16x8*)&zt[(size_t)p * 360 + oc * 8];
        #pragma unroll
        for (int j = 0; j < 8; ++j) {
            float v = bf2f(t[j]);
            s[j] += v; q[j] += v * v;
        }
    }
    float* pr = part + ((size_t)stripe * 45 + oc) * 16;
    #pragma unroll
    for (int j = 0; j < 8; ++j) { pr[j] = s[j]; pr[8 + j] = q[j]; }
}

__global__ __launch_bounds__(256) void bn_fin(const float* __restrict__ part,
                                              const float* __restrict__ g,
                                              const float* __restrict__ bb,
                                              float* __restrict__ sc,
                                              float* __restrict__ sh)
{
    const int oc = blockIdx.x;
    const int t  = threadIdx.x;
    const float* p1 = part + ((size_t)t * 45 + oc) * 16;
    const float* p2 = part + ((size_t)(t + 256) * 45 + oc) * 16;
    float v[16];
    #pragma unroll
    for (int k = 0; k < 16; ++k) v[k] = p1[k] + p2[k];
    #pragma unroll
    for (int k = 0; k < 16; ++k)
        for (int m = 32; m; m >>= 1) v[k] += __shfl_xor(v[k], m, 64);
    __shared__ float red[4][16];
    if ((t & 63) == 0) {
        #pragma unroll
        for (int k = 0; k < 16; ++k) red[t >> 6][k] = v[k];
    }
    __syncthreads();
    if (t == 0) {
        const float invN = 1.f / (float)NPIX;
        #pragma unroll
        for (int j = 0; j < 8; ++j) {
            const int c = oc * 8 + j;
            float su = red[0][j] + red[1][j] + red[2][j] + red[3][j];
            float sq = red[0][8+j] + red[1][8+j] + red[2][8+j] + red[3][8+j];
            float mean = su * invN;
            float var  = sq * invN - mean * mean;
            float istd = 1.f / sqrtf(var + 1e-5f);
            float s = g[c] * istd;
            sc[c] = s;
            sh[c] = bb[c] - mean * s;
        }
    }
}

// ---------------------------------------------------------------------------
// attn_v3 (verbatim r17/r23)
// ---------------------------------------------------------------------------
template<int WS>
__global__ __launch_bounds__(256) void attn_v3(
    const u16* __restrict__ zt, const float* __restrict__ scale,
    const float* __restrict__ shiftc, u16* __restrict__ ot, int chunk)
{
    constexpr int NP  = WS * WS;
    constexpr int GPB = 256 / NP;
    constexpr int SH  = WS / 2;
    constexpr int NW  = 256 / WS;

    __shared__ float qs[256 * 12];
    __shared__ float vs[256 * 12];
    __shared__ float scs[120], shs[120];

    const int tid = threadIdx.x;
    if (tid < 120) {
        scs[tid] = scale[chunk * 120 + tid];
        shs[tid] = shiftc[chunk * 120 + tid];
    }

    const int lg  = tid / NP;
    const int n   = tid % NP;
    const int gidx = blockIdx.x * GPB + lg;

    const int head = gidx % 6;
    const int win  = gidx / 6;
    const int wcol = win % NW;
    const int tmp  = win / NW;
    const int wrow = tmp % NW;
    const int b    = tmp / NW;

    const int i = n / WS, j = n % WS;
    const int hh = (wrow * WS + i + SH) & 255;
    const int ww = (wcol * WS + j + SH) & 255;
    const size_t zrow = (size_t)((b << 16) | (hh << 8) | ww) * 360;

    const int cq = chunk * 120 + head * 10;
    const int cl = head * 10;

    u16x8u q8 = *(const u16x8u*)&zt[zrow + cq];
    u16x2  q2 = *(const u16x2*)&zt[zrow + cq + 8];
    u16x8u v8 = *(const u16x8u*)&zt[zrow + cq + 60];
    u16x2  v2 = *(const u16x2*)&zt[zrow + cq + 68];
    __syncthreads();

    float q[10];
    float* qrow = &qs[tid * 12];
    float* vrow = &vs[tid * 12];
    #pragma unroll
    for (int c = 0; c < 8; ++c) {
        q[c] = bf2f(q8[c]) * scs[cl + c] + shs[cl + c];
        qrow[c] = q[c];
        vrow[c] = bf2f(v8[c]) * scs[60 + cl + c] + shs[60 + cl + c];
    }
    q[8] = bf2f(q2[0]) * scs[cl + 8] + shs[cl + 8];
    q[9] = bf2f(q2[1]) * scs[cl + 9] + shs[cl + 9];
    qrow[8] = q[8]; qrow[9] = q[9];
    vrow[8] = bf2f(v2[0]) * scs[60 + cl + 8] + shs[60 + cl + 8];
    vrow[9] = bf2f(v2[1]) * scs[60 + cl + 9] + shs[60 + cl + 9];
    qrow[10] = 0.f; qrow[11] = 0.f;
    vrow[10] = 0.f; vrow[11] = 0.f;
    __syncthreads();

    const float* qg = &qs[(lg * NP) * 12];
    const float* vg = &vs[(lg * NP) * 12];

    float mx = -1e30f;
    for (int m = 0; m < NP; ++m) {
        f32x4 a0 = *(const f32x4*)&qg[m * 12];
        f32x4 a1 = *(const f32x4*)&qg[m * 12 + 4];
        f32x4 a2 = *(const f32x4*)&qg[m * 12 + 8];
        float d = q[0]*a0[0] + q[1]*a0[1] + q[2]*a0[2] + q[3]*a0[3]
                + q[4]*a1[0] + q[5]*a1[1] + q[6]*a1[2] + q[7]*a1[3]
                + q[8]*a2[0] + q[9]*a2[1];
        mx = fmaxf(mx, d);
    }
    float s = 0.f;
    float o[10] = {};
    for (int m = 0; m < NP; ++m) {
        f32x4 a0 = *(const f32x4*)&qg[m * 12];
        f32x4 a1 = *(const f32x4*)&qg[m * 12 + 4];
        f32x4 a2 = *(const f32x4*)&qg[m * 12 + 8];
        float d = q[0]*a0[0] + q[1]*a0[1] + q[2]*a0[2] + q[3]*a0[3]
                + q[4]*a1[0] + q[5]*a1[1] + q[6]*a1[2] + q[7]*a1[3]
                + q[8]*a2[0] + q[9]*a2[1];
        float e = __expf(d - mx);
        s += e;
        f32x4 b0 = *(const f32x4*)&vg[m * 12];
        f32x4 b1 = *(const f32x4*)&vg[m * 12 + 4];
        f32x4 b2 = *(const f32x4*)&vg[m * 12 + 8];
        o[0] += e * b0[0]; o[1] += e * b0[1]; o[2] += e * b0[2]; o[3] += e * b0[3];
        o[4] += e * b1[0]; o[5] += e * b1[1]; o[6] += e * b1[2]; o[7] += e * b1[3];
        o[8] += e * b2[0]; o[9] += e * b2[1];
    }
    const float inv = 1.f / s;
    u16* orow = ot + (size_t)((b << 16) | (hh << 8) | ww) * 180 + chunk * 60 + head * 10;
    u16x8u o8;
    #pragma unroll
    for (int c = 0; c < 8; ++c) o8[c] = f2bf(o[c] * inv);
    u16x2 o2;
    o2[0] = f2bf(o[8] * inv);
    o2[1] = f2bf(o[9] * inv);
    *(u16x8u*)&orow[0] = o8;
    *(u16x2*)&orow[8]  = o2;
}

// ---------------------------------------------------------------------------
extern "C" void kernel_launch(void* const* d_in, const int* in_sizes, int n_in,
                              void* d_out, int out_size, void* d_ws, size_t ws_size,
                              hipStream_t stream)
{
    const float* x     = (const float*)d_in[0];
    const float* w0    = (const float*)d_in[1];
    const float* b0    = (const float*)d_in[2];
    const float* w1    = (const float*)d_in[3];
    const float* b1    = (const float*)d_in[4];
    const float* w_in  = (const float*)d_in[5];
    const float* b_in  = (const float*)d_in[6];
    const float* bn_g  = (const float*)d_in[7];
    const float* bn_b  = (const float*)d_in[8];
    const float* w_out = (const float*)d_in[9];
    const float* b_out = (const float*)d_in[10];
    float* out = (float*)d_out;

    u16* y   = (u16*)d_ws;                      // [131072][360] (later zt)
    u16* x1b = y   + (size_t)NPIX * 360;        // [131072][180]
    u16* ot  = x1b + (size_t)NPIX * 180;        // [131072][180]
    u16* W0p = ot  + (size_t)NPIX * 180;        // 384x192
    u16* Wip = W0p + 384 * 192;                 // 384x192
    u16* W1p = Wip + 384 * 192;                 // 192x384
    u16* Wop = W1p + 192 * 384;                 // 192x192
    float* part   = (float*)(Wop + 192 * 192);  // 512*45*16
    float* scale  = part + 512 * 45 * 16;
    float* shiftc = scale + 360;
    u16* zt = y;

    dim3 blk(256);
    dim3 blk8(512);

    prep_w<<<dim3(288), blk, 0, stream>>>(w0, w1, w_in, w_out, W0p, W1p, Wip, Wop);

    // conv1 (v14, 8-wave full-M): y = relu(W0 @ shift(x) + b0) -> y NHWC360
    conv_v14<180, 36, 0, 0,   true >
        <<<dim3(2048), blk8, 0, stream>>>(x, W0p, b0, y);
    // conv2 (v10): x1 = W1 @ shift(y) + b1 + x                 -> x1b NHWC180
    conv_v10<360, 180, 72, 360, false, 1, 1, 180, false>
        <<<dim3(2048, 1), blk, 0, stream>>>(y, W1p, b1, x, x1b);
    // conv3 (v14, 8-wave full-M): z = W_in @ x1 + b_in         -> zt NHWC360
    conv_v14<180, 0,  1, 180, false>
        <<<dim3(2048), blk8, 0, stream>>>(x1b, Wip, b_in, zt);
    // BN statistics
    bn_part<<<dim3(128), blk, 0, stream>>>(zt, part);
    bn_fin<<<dim3(45), blk, 0, stream>>>(part, bn_g, bn_b, scale, shiftc);
    // window attention -> ot NHWC180
    attn_v3<2><<<dim3(3072), blk, 0, stream>>>(zt, scale, shiftc, ot, 0);
    attn_v3<4><<<dim3(3072), blk, 0, stream>>>(zt, scale, shiftc, ot, 1);
    attn_v3<8><<<dim3(3072), blk, 0, stream>>>(zt, scale, shiftc, ot, 2);
    // conv4 (v10): out = W_out @ ot + b_out + x1               -> out fp32 NCHW
    conv_v10<180, 180, 0,  180, false, 2, 0, 0, false>
        <<<dim3(2048, 1), blk, 0, stream>>>(ot, Wop, b_out, x1b, out);
}

// Round 25
// 386.994 us; speedup vs baseline: 3.5740x; 1.0297x over previous
//
#include <hip/hip_runtime.h>
#include <hip/hip_bf16.h>

#define HWSZ 65536   // 256*256
#define NPIX 131072  // 2 * HWSZ

typedef unsigned short u16;
typedef __bf16 bf16x8 __attribute__((ext_vector_type(8)));
typedef float f32x4 __attribute__((ext_vector_type(4)));
typedef unsigned short u16x2 __attribute__((ext_vector_type(2)));
typedef unsigned short u16x4 __attribute__((ext_vector_type(4)));
typedef unsigned short u16x8 __attribute__((ext_vector_type(8)));
typedef unsigned short u16x8u __attribute__((ext_vector_type(8), aligned(4)));

__device__ inline u16 f2bf(float f) {
    unsigned int x = __builtin_bit_cast(unsigned int, f);
    unsigned int r = x + 0x7FFFu + ((x >> 16) & 1u);
    return (u16)(r >> 16);
}
__device__ inline float bf2f(u16 u) {
    unsigned int x = ((unsigned int)u) << 16;
    return __builtin_bit_cast(float, x);
}

// ---------------------------------------------------------------------------
// Weight prep (verbatim r5-r24)
// ---------------------------------------------------------------------------
__global__ __launch_bounds__(256) void prep_w(
    const float* __restrict__ w0, const float* __restrict__ w1,
    const float* __restrict__ wi, const float* __restrict__ wo,
    u16* __restrict__ W0p, u16* __restrict__ W1p,
    u16* __restrict__ Wip, u16* __restrict__ Wop)
{
    const int i = blockIdx.x * 256 + threadIdx.x;   // < 73728
    {
        const int r = i / 192, c = i % 192;
        const bool ok = (r < 360) && (c < 180);
        W0p[i] = ok ? f2bf(w0[r * 180 + c]) : (u16)0;
        Wip[i] = ok ? f2bf(wi[r * 180 + c]) : (u16)0;
    }
    {
        const int r = i / 384, c = i % 384;
        W1p[i] = (r < 180 && c < 360) ? f2bf(w1[r * 360 + c]) : (u16)0;
    }
    if (i < 36864) {
        const int r = i / 192, c = i % 192;
        Wop[i] = (r < 180 && c < 180) ? f2bf(wo[r * 180 + c]) : (u16)0;
    }
}

// ---------------------------------------------------------------------------
// conv_v14 (r24 + optional fused BN partial stats).
// 8-wave (512-thread) full-M conv for CO=360 (padded 384).
// One block = ALL co rows x 64 px; X staged ONCE per K-step.
// BNPART: epilogue accumulates per-block sum/sumsq of the bf16 outputs into
// part[block*768 + c] (sum) and part[block*768 + 384 + c] (sumsq).
// ---------------------------------------------------------------------------
template<int CI, int G, int INM, int XSTR, bool RELU, bool BNPART>
__global__ __launch_bounds__(512) void conv_v14(
    const void* __restrict__ Xv, const u16* __restrict__ Wp,
    const float* __restrict__ bias, u16* __restrict__ Yh,
    float* __restrict__ part)
{
    constexpr int CI_PAD = ((CI + 31) / 32) * 32;
    constexpr int NSTEP  = CI_PAD / 32;
    constexpr int LDK    = 40;

    __shared__ u16 Xt[2][64 * LDK];   // 2 x 5120 B

    const int tid = threadIdx.x;
    const int p0   = blockIdx.x << 6;
    const int b    = p0 >> 16;
    const int pix0 = p0 & 65535;
    const int h    = pix0 >> 8;
    const int w0c  = pix0 & 255;
    const int lane = tid & 63, wid = tid >> 6;   // wid 0..7
    const int lr = lane & 15, lg = lane >> 4;
    const int co_wave = wid * 48;                 // 0..336

    const float* Xf = (const float*)Xv + (size_t)b * CI * HWSZ;
    const u16*   Xh = (const u16*)Xv;

    const int xn  = tid & 63;    // pixel this thread stages
    const int k4a = tid >> 6;    // k-quad 0..7 (32 ch / 4)

    auto loadX = [&](int kt, u16x4& r) {
        const int c0 = kt + k4a * 4;
        u16x4 v = {0, 0, 0, 0};
        if (c0 < CI) {
            int dh = 0, dw = 0;
            if (G > 0) {                    // 4|G: quad shift-uniform
                const int g = c0 / G;
                if      (g == 0) dw = 1;
                else if (g == 1) dw = -1;
                else if (g == 2) dh = 1;
                else if (g == 3) dh = -1;
            }
            const int hh = h + dh;
            const int wp = w0c + xn + dw;
            if (hh >= 0 && hh < 256 && wp >= 0 && wp < 256) {
                if constexpr (INM == 1) {
                    v = *(const u16x4*)&Xh[(size_t)((b << 16) | (hh << 8) | wp) * XSTR + c0];
                } else {
                    const float* xs = Xf + (size_t)c0 * HWSZ + hh * 256 + wp;
                    #pragma unroll
                    for (int j = 0; j < 4; ++j) v[j] = f2bf(xs[(size_t)j * HWSZ]);
                }
            }
        }
        r = v;
    };

    auto loadW = [&](int kt, bf16x8 (&a)[3]) {
        #pragma unroll
        for (int mf = 0; mf < 3; ++mf)
            a[mf] = *(const bf16x8*)&Wp[(size_t)(co_wave + mf * 16 + lr) * CI_PAD + kt + lg * 8];
    };

    auto writeLDS = [&](u16x4& r, int buf) {
        *(u16x4*)&Xt[buf][xn * LDK + k4a * 4] = r;
    };

    f32x4 acc[3][4] = {};
    u16x4 raw[2];
    bf16x8 af[2][3];

    loadX(0, raw[0]);
    loadW(0, af[0]);
    writeLDS(raw[0], 0);

    #pragma unroll
    for (int s = 0; s < NSTEP; ++s) {
        const int cur = s & 1, nxt = cur ^ 1;
        __syncthreads();                      // Xt[cur] ready for all 8 waves
        if (s + 1 < NSTEP) {
            loadX((s + 1) * 32, raw[nxt]);
            loadW((s + 1) * 32, af[nxt]);
        }
        bf16x8 bfr[4];
        #pragma unroll
        for (int nf = 0; nf < 4; ++nf)
            bfr[nf] = *(const bf16x8*)&Xt[cur][(nf * 16 + lr) * LDK + lg * 8];
        #pragma unroll
        for (int mf = 0; mf < 3; ++mf)
            #pragma unroll
            for (int nf = 0; nf < 4; ++nf)
                acc[mf][nf] = __builtin_amdgcn_mfma_f32_16x16x32_bf16(
                    af[cur][mf], bfr[nf], acc[mf][nf], 0, 0, 0);
        if (s + 1 < NSTEP) writeLDS(raw[nxt], nxt);
    }

    // epilogue: co = co_wave + mf*16 + lg*4 + r, pixel = p0 + nf*16 + lr
    float bsum[3][4] = {}, bsq[3][4] = {};
    #pragma unroll
    for (int mf = 0; mf < 3; ++mf) {
        const int co_b = co_wave + mf * 16 + lg * 4;
        if (co_b >= 360) continue;
        #pragma unroll
        for (int nf = 0; nf < 4; ++nf) {
            const size_t pg = (size_t)p0 + nf * 16 + lr;
            u16x4 o;
            #pragma unroll
            for (int r = 0; r < 4; ++r) {
                float v = acc[mf][nf][r] + bias[co_b + r];
                if (RELU) v = fmaxf(v, 0.f);
                o[r] = f2bf(v);
                if (BNPART) {
                    const float vr = bf2f(o[r]);
                    bsum[mf][r] += vr;
                    bsq[mf][r]  += vr * vr;
                }
            }
            *(u16x4*)&Yh[pg * 360 + co_b] = o;
        }
    }

    if (BNPART) {
        // reduce over the 16 lr lanes (masks 1,2,4,8 stay within the lr group)
        #pragma unroll
        for (int mf = 0; mf < 3; ++mf)
            #pragma unroll
            for (int r = 0; r < 4; ++r) {
                #pragma unroll
                for (int m = 1; m < 16; m <<= 1) {
                    bsum[mf][r] += __shfl_xor(bsum[mf][r], m, 64);
                    bsq[mf][r]  += __shfl_xor(bsq[mf][r],  m, 64);
                }
            }
        if (lr == 0) {
            float* pb = part + (size_t)blockIdx.x * 768;
            #pragma unroll
            for (int mf = 0; mf < 3; ++mf) {
                const int co_b = co_wave + mf * 16 + lg * 4;
                if (co_b >= 360) continue;
                f32x4 s4, q4;
                #pragma unroll
                for (int r = 0; r < 4; ++r) { s4[r] = bsum[mf][r]; q4[r] = bsq[mf][r]; }
                *(f32x4*)&pb[co_b]       = s4;
                *(f32x4*)&pb[384 + co_b] = q4;
            }
        }
    }
}

// ---------------------------------------------------------------------------
// bn_fin2: reduce 2048 per-block partials -> fused scale/shift. grid 360.
// ---------------------------------------------------------------------------
__global__ __launch_bounds__(256) void bn_fin2(const float* __restrict__ part,
                                               const float* __restrict__ g,
                                               const float* __restrict__ bb,
                                               float* __restrict__ sc,
                                               float* __restrict__ sh)
{
    const int c = blockIdx.x;    // 0..359
    const int t = threadIdx.x;
    float s = 0.f, q = 0.f;
    for (int k = t; k < 2048; k += 256) {
        s += part[(size_t)k * 768 + c];
        q += part[(size_t)k * 768 + 384 + c];
    }
    for (int m = 32; m; m >>= 1) {
        s += __shfl_xor(s, m, 64);
        q += __shfl_xor(q, m, 64);
    }
    __shared__ float rs[4], rq[4];
    if ((t & 63) == 0) { rs[t >> 6] = s; rq[t >> 6] = q; }
    __syncthreads();
    if (t == 0) {
        const float su = rs[0] + rs[1] + rs[2] + rs[3];
        const float sq = rq[0] + rq[1] + rq[2] + rq[3];
        const float invN = 1.f / (float)NPIX;
        const float mean = su * invN;
        const float var  = sq * invN - mean * mean;
        const float istd = 1.f / sqrtf(var + 1e-5f);
        const float scv  = g[c] * istd;
        sc[c] = scv;
        sh[c] = bb[c] - mean * scv;
    }
}

// ---------------------------------------------------------------------------
// conv_v10 (verbatim r23/r24): global_load_lds staging conv (NHWC bf16 input).
// ---------------------------------------------------------------------------
template<int CI, int CO, int G, int XSTR, bool RELU, int RES, int OUTM, int OSTR, bool COSPLIT>
__global__ __launch_bounds__(256) void conv_v10(
    const u16* __restrict__ Xh, const u16* __restrict__ Wp,
    const float* __restrict__ bias, const void* __restrict__ Rv,
    void* __restrict__ Yv)
{
    constexpr int CI_PAD = ((CI + 31) / 32) * 32;
    constexpr int NSTEP  = CI_PAD / 32;

    __shared__ u16 Xt[2][256 * 8];   // 2 x 4 KB

    const int tid = threadIdx.x;
    const int bid = blockIdx.x;
    int px_tile, co0;
    if (COSPLIT) {
        co0     = ((bid >> 3) & 1) * 192;
        px_tile = ((bid >> 4) << 3) | (bid & 7);
    } else {
        co0 = blockIdx.y * 192; px_tile = bid;
    }
    const int p0   = px_tile << 6;
    const int b    = p0 >> 16;
    const int pix0 = p0 & 65535;
    const int h    = pix0 >> 8;
    const int w0c  = pix0 & 255;
    const int lane = tid & 63, wid = tid >> 6;
    const int lr = lane & 15, lg = lane >> 4;
    const int co_wave = co0 + wid * 48;

    const int sg  = (wid << 6) | lane;
    const int spx = sg >> 2;
    const int khp = sg & 3;
    const int kh  = khp ^ ((spx >> 1) & 3);

    auto stage = [&](int kt, int buf) {
        const int c0 = kt + kh * 8;
        u16* ldst_lane = &Xt[buf][sg * 8];
        int dh = 0, dw = 0; bool uni = true;
        if (G > 0) {
            const int g0 = c0 / G;
            uni = (g0 == (c0 + 7) / G);
            if      (g0 == 0) dw = 1;
            else if (g0 == 1) dw = -1;
            else if (g0 == 2) dh = 1;
            else if (g0 == 3) dh = -1;
        }
        const int hh = h + dh, wp = w0c + spx + dw;
        const bool pxok = (hh >= 0 && hh < 256 && wp >= 0 && wp < 256);
        if (c0 < CI && uni && pxok) {
            const u16* src = &Xh[(size_t)((b << 16) | (hh << 8) | wp) * XSTR + c0];
            u16* wbase = &Xt[buf][(wid << 6) * 8];
            __builtin_amdgcn_global_load_lds(
                (const __attribute__((address_space(1))) unsigned int*)src,
                (__attribute__((address_space(3))) unsigned int*)wbase, 16, 0, 0);
        } else {
            u16x8 t = {0, 0, 0, 0, 0, 0, 0, 0};
            if (c0 < CI && pxok) {
                #pragma unroll
                for (int j = 0; j < 8; ++j) {
                    const int c = c0 + j;
                    if (c < CI) {
                        int dh2 = 0, dw2 = 0;
                        if (G > 0) {
                            const int g = c / G;
                            if      (g == 0) dw2 = 1;
                            else if (g == 1) dw2 = -1;
                            else if (g == 2) dh2 = 1;
                            else if (g == 3) dh2 = -1;
                        }
                        const int h2 = h + dh2, w2 = w0c + spx + dw2;
                        if (h2 >= 0 && h2 < 256 && w2 >= 0 && w2 < 256)
                            t[j] = Xh[(size_t)((b << 16) | (h2 << 8) | w2) * XSTR + c];
                    }
                }
            }
            *(u16x8*)ldst_lane = t;
        }
    };

    auto loadW = [&](int kt, bf16x8 (&a)[3]) {
        #pragma unroll
        for (int mf = 0; mf < 3; ++mf)
            a[mf] = *(const bf16x8*)&Wp[(size_t)(co_wave + mf * 16 + lr) * CI_PAD + kt + lg * 8];
    };

    f32x4 acc[3][4] = {};
    bf16x8 af[2][3];

    stage(0, 0);
    loadW(0, af[0]);
    __syncthreads();

    #pragma unroll
    for (int s = 0; s < NSTEP; ++s) {
        const int cur = s & 1, nxt = cur ^ 1;
        if (s + 1 < NSTEP) {
            stage((s + 1) * 32, nxt);
            loadW((s + 1) * 32, af[nxt]);
        }
        bf16x8 bfr[4];
        #pragma unroll
        for (int nf = 0; nf < 4; ++nf) {
            const int pxr = nf * 16 + lr;
            const int kpp = lg ^ ((pxr >> 1) & 3);
            bfr[nf] = *(const bf16x8*)&Xt[cur][pxr * 32 + kpp * 8];
        }
        #pragma unroll
        for (int mf = 0; mf < 3; ++mf)
            #pragma unroll
            for (int nf = 0; nf < 4; ++nf)
                acc[mf][nf] = __builtin_amdgcn_mfma_f32_16x16x32_bf16(
                    af[cur][mf], bfr[nf], acc[mf][nf], 0, 0, 0);
        __syncthreads();
    }

    const float* Rf = (const float*)Rv;
    const u16*   Rh = (const u16*)Rv;
    #pragma unroll
    for (int mf = 0; mf < 3; ++mf) {
        const int co_b = co_wave + mf * 16 + lg * 4;
        if (co_b >= CO) continue;
        #pragma unroll
        for (int nf = 0; nf < 4; ++nf) {
            const int pl = pix0 + nf * 16 + lr;
            const size_t pg = (size_t)p0 + nf * 16 + lr;
            float v[4];
            #pragma unroll
            for (int r = 0; r < 4; ++r) {
                v[r] = acc[mf][nf][r] + bias[co_b + r];
                if (RELU) v[r] = fmaxf(v[r], 0.f);
            }
            if (RES == 1) {
                #pragma unroll
                for (int r = 0; r < 4; ++r)
                    v[r] += Rf[((size_t)(b * CO + co_b + r)) * HWSZ + pl];
            }
            if (RES == 2) {
                u16x4 rr = *(const u16x4*)&Rh[pg * 180 + co_b];
                #pragma unroll
                for (int r = 0; r < 4; ++r) v[r] += bf2f(rr[r]);
            }
            if (OUTM == 1) {
                u16x4 o;
                #pragma unroll
                for (int r = 0; r < 4; ++r) o[r] = f2bf(v[r]);
                *(u16x4*)&((u16*)Yv)[pg * OSTR + co_b] = o;
            } else {
                #pragma unroll
                for (int r = 0; r < 4; ++r)
                    ((float*)Yv)[((size_t)(b * CO + co_b + r)) * HWSZ + pl] = v[r];
            }
        }
    }
}

// ---------------------------------------------------------------------------
// attn_v3 (verbatim r17/r24)
// ---------------------------------------------------------------------------
template<int WS>
__global__ __launch_bounds__(256) void attn_v3(
    const u16* __restrict__ zt, const float* __restrict__ scale,
    const float* __restrict__ shiftc, u16* __restrict__ ot, int chunk)
{
    constexpr int NP  = WS * WS;
    constexpr int GPB = 256 / NP;
    constexpr int SH  = WS / 2;
    constexpr int NW  = 256 / WS;

    __shared__ float qs[256 * 12];
    __shared__ float vs[256 * 12];
    __shared__ float scs[120], shs[120];

    const int tid = threadIdx.x;
    if (tid < 120) {
        scs[tid] = scale[chunk * 120 + tid];
        shs[tid] = shiftc[chunk * 120 + tid];
    }

    const int lg  = tid / NP;
    const int n   = tid % NP;
    const int gidx = blockIdx.x * GPB + lg;

    const int head = gidx % 6;
    const int win  = gidx / 6;
    const int wcol = win % NW;
    const int tmp  = win / NW;
    const int wrow = tmp % NW;
    const int b    = tmp / NW;

    const int i = n / WS, j = n % WS;
    const int hh = (wrow * WS + i + SH) & 255;
    const int ww = (wcol * WS + j + SH) & 255;
    const size_t zrow = (size_t)((b << 16) | (hh << 8) | ww) * 360;

    const int cq = chunk * 120 + head * 10;
    const int cl = head * 10;

    u16x8u q8 = *(const u16x8u*)&zt[zrow + cq];
    u16x2  q2 = *(const u16x2*)&zt[zrow + cq + 8];
    u16x8u v8 = *(const u16x8u*)&zt[zrow + cq + 60];
    u16x2  v2 = *(const u16x2*)&zt[zrow + cq + 68];
    __syncthreads();

    float q[10];
    float* qrow = &qs[tid * 12];
    float* vrow = &vs[tid * 12];
    #pragma unroll
    for (int c = 0; c < 8; ++c) {
        q[c] = bf2f(q8[c]) * scs[cl + c] + shs[cl + c];
        qrow[c] = q[c];
        vrow[c] = bf2f(v8[c]) * scs[60 + cl + c] + shs[60 + cl + c];
    }
    q[8] = bf2f(q2[0]) * scs[cl + 8] + shs[cl + 8];
    q[9] = bf2f(q2[1]) * scs[cl + 9] + shs[cl + 9];
    qrow[8] = q[8]; qrow[9] = q[9];
    vrow[8] = bf2f(v2[0]) * scs[60 + cl + 8] + shs[60 + cl + 8];
    vrow[9] = bf2f(v2[1]) * scs[60 + cl + 9] + shs[60 + cl + 9];
    qrow[10] = 0.f; qrow[11] = 0.f;
    vrow[10] = 0.f; vrow[11] = 0.f;
    __syncthreads();

    const float* qg = &qs[(lg * NP) * 12];
    const float* vg = &vs[(lg * NP) * 12];

    float mx = -1e30f;
    for (int m = 0; m < NP; ++m) {
        f32x4 a0 = *(const f32x4*)&qg[m * 12];
        f32x4 a1 = *(const f32x4*)&qg[m * 12 + 4];
        f32x4 a2 = *(const f32x4*)&qg[m * 12 + 8];
        float d = q[0]*a0[0] + q[1]*a0[1] + q[2]*a0[2] + q[3]*a0[3]
                + q[4]*a1[0] + q[5]*a1[1] + q[6]*a1[2] + q[7]*a1[3]
                + q[8]*a2[0] + q[9]*a2[1];
        mx = fmaxf(mx, d);
    }
    float s = 0.f;
    float o[10] = {};
    for (int m = 0; m < NP; ++m) {
        f32x4 a0 = *(const f32x4*)&qg[m * 12];
        f32x4 a1 = *(const f32x4*)&qg[m * 12 + 4];
        f32x4 a2 = *(const f32x4*)&qg[m * 12 + 8];
        float d = q[0]*a0[0] + q[1]*a0[1] + q[2]*a0[2] + q[3]*a0[3]
                + q[4]*a1[0] + q[5]*a1[1] + q[6]*a1[2] + q[7]*a1[3]
                + q[8]*a2[0] + q[9]*a2[1];
        float e = __expf(d - mx);
        s += e;
        f32x4 b0 = *(const f32x4*)&vg[m * 12];
        f32x4 b1 = *(const f32x4*)&vg[m * 12 + 4];
        f32x4 b2 = *(const f32x4*)&vg[m * 12 + 8];
        o[0] += e * b0[0]; o[1] += e * b0[1]; o[2] += e * b0[2]; o[3] += e * b0[3];
        o[4] += e * b1[0]; o[5] += e * b1[1]; o[6] += e * b1[2]; o[7] += e * b1[3];
        o[8] += e * b2[0]; o[9] += e * b2[1];
    }
    const float inv = 1.f / s;
    u16* orow = ot + (size_t)((b << 16) | (hh << 8) | ww) * 180 + chunk * 60 + head * 10;
    u16x8u o8;
    #pragma unroll
    for (int c = 0; c < 8; ++c) o8[c] = f2bf(o[c] * inv);
    u16x2 o2;
    o2[0] = f2bf(o[8] * inv);
    o2[1] = f2bf(o[9] * inv);
    *(u16x8u*)&orow[0] = o8;
    *(u16x2*)&orow[8]  = o2;
}

// ---------------------------------------------------------------------------
extern "C" void kernel_launch(void* const* d_in, const int* in_sizes, int n_in,
                              void* d_out, int out_size, void* d_ws, size_t ws_size,
                              hipStream_t stream)
{
    const float* x     = (const float*)d_in[0];
    const float* w0    = (const float*)d_in[1];
    const float* b0    = (const float*)d_in[2];
    const float* w1    = (const float*)d_in[3];
    const float* b1    = (const float*)d_in[4];
    const float* w_in  = (const float*)d_in[5];
    const float* b_in  = (const float*)d_in[6];
    const float* bn_g  = (const float*)d_in[7];
    const float* bn_b  = (const float*)d_in[8];
    const float* w_out = (const float*)d_in[9];
    const float* b_out = (const float*)d_in[10];
    float* out = (float*)d_out;

    u16* y   = (u16*)d_ws;                      // [131072][360] (later zt)
    u16* x1b = y   + (size_t)NPIX * 360;        // [131072][180]
    u16* ot  = x1b + (size_t)NPIX * 180;        // [131072][180]
    u16* W0p = ot  + (size_t)NPIX * 180;        // 384x192
    u16* Wip = W0p + 384 * 192;                 // 384x192
    u16* W1p = Wip + 384 * 192;                 // 192x384
    u16* Wop = W1p + 192 * 384;                 // 192x192
    float* part   = (float*)(Wop + 192 * 192);  // 2048*768 floats (6.3 MB)
    float* scale  = part + (size_t)2048 * 768;
    float* shiftc = scale + 360;
    u16* zt = y;

    dim3 blk(256);
    dim3 blk8(512);

    prep_w<<<dim3(288), blk, 0, stream>>>(w0, w1, w_in, w_out, W0p, W1p, Wip, Wop);

    // conv1 (v14): y = relu(W0 @ shift(x) + b0)                -> y NHWC360
    conv_v14<180, 36, 0, 0,   true,  false>
        <<<dim3(2048), blk8, 0, stream>>>(x, W0p, b0, y, nullptr);
    // conv2 (v10): x1 = W1 @ shift(y) + b1 + x                 -> x1b NHWC180
    conv_v10<360, 180, 72, 360, false, 1, 1, 180, false>
        <<<dim3(2048, 1), blk, 0, stream>>>(y, W1p, b1, x, x1b);
    // conv3 (v14 + fused BN partials): z = W_in @ x1 + b_in    -> zt NHWC360
    conv_v14<180, 0,  1, 180, false, true >
        <<<dim3(2048), blk8, 0, stream>>>(x1b, Wip, b_in, zt, part);
    // BN finalize from fused partials
    bn_fin2<<<dim3(360), blk, 0, stream>>>(part, bn_g, bn_b, scale, shiftc);
    // window attention -> ot NHWC180
    attn_v3<2><<<dim3(3072), blk, 0, stream>>>(zt, scale, shiftc, ot, 0);
    attn_v3<4><<<dim3(3072), blk, 0, stream>>>(zt, scale, shiftc, ot, 1);
    attn_v3<8><<<dim3(3072), blk, 0, stream>>>(zt, scale, shiftc, ot, 2);
    // conv4 (v10): out = W_out @ ot + b_out + x1               -> out fp32 NCHW
    conv_v10<180, 180, 0,  180, false, 2, 0, 0, false>
        <<<dim3(2048, 1), blk, 0, stream>>>(ot, Wop, b_out, x1b, out);
}